// Round 2
// baseline (1999.091 us; speedup 1.0000x reference)
//
#include <hip/hip_runtime.h>
#include <cstdint>

typedef unsigned short u16;
typedef __attribute__((ext_vector_type(8))) short short8;
typedef __attribute__((ext_vector_type(4))) float f32x4;

#define MFMA_16x16x32(a,b,c) __builtin_amdgcn_mfma_f32_16x16x32_bf16(a,b,c,0,0,0)

#define BB 2
#define SS 1024
#define DD 2048
#define HH 16
#define HKK 4
#define HDD 128
#define EE 16
#define NTOP 6
#define II 1024
#define ISS 2048
#define TT 2048
#define CAP 2048

__device__ __forceinline__ u16 f2b(float f) {
    union { float f; uint32_t u; } v; v.f = f;
    uint32_t r = v.u + 0x7FFFu + ((v.u >> 16) & 1u);
    return (u16)(r >> 16);
}
__device__ __forceinline__ float b2f(u16 h) {
    union { uint32_t u; float f; } v; v.u = ((uint32_t)h) << 16;
    return v.f;
}
__device__ __forceinline__ void fsplit(float f, u16& hi, u16& lo) {
    u16 h = f2b(f);
    hi = h;
    lo = f2b(f - b2f(h));
}

// ---------------- RMSNorm f32 in -> split bf16 (hi,lo) ----------------------
__global__ __launch_bounds__(256) void k_rmsnorm_split(
    const float* __restrict__ X, const float* __restrict__ Wt,
    u16* __restrict__ Oh, u16* __restrict__ Ol)
{
    const int t = blockIdx.x;
    const float* x = X + (size_t)t * DD;
    const int base = threadIdx.x * 8;
    f32x4 v0 = *(const f32x4*)(x + base);
    f32x4 v1 = *(const f32x4*)(x + base + 4);
    float ss = 0.f;
    #pragma unroll
    for (int j = 0; j < 4; ++j) ss += v0[j]*v0[j] + v1[j]*v1[j];
    #pragma unroll
    for (int o = 1; o < 64; o <<= 1) ss += __shfl_xor(ss, o);
    __shared__ float red[4];
    if ((threadIdx.x & 63) == 0) red[threadIdx.x >> 6] = ss;
    __syncthreads();
    float tot = red[0] + red[1] + red[2] + red[3];
    float inv = rsqrtf(tot * (1.0f/DD) + 1e-6f);
    f32x4 w0 = *(const f32x4*)(Wt + base);
    f32x4 w1 = *(const f32x4*)(Wt + base + 4);
    u16* oh = Oh + (size_t)t*DD + base;
    u16* ol = Ol + (size_t)t*DD + base;
    #pragma unroll
    for (int j = 0; j < 4; ++j) {
        float y0 = v0[j]*inv*w0[j];
        float y1 = v1[j]*inv*w1[j];
        fsplit(y0, oh[j],   ol[j]);
        fsplit(y1, oh[4+j], ol[4+j]);
    }
}

// ---------------- RMSNorm f32 in -> bf16 + f32 ------------------------------
__global__ __launch_bounds__(256) void k_rmsnorm_bf(
    const float* __restrict__ X, const float* __restrict__ Wt,
    u16* __restrict__ Ob, float* __restrict__ Of)
{
    const int t = blockIdx.x;
    const float* x = X + (size_t)t * DD;
    const int base = threadIdx.x * 8;
    f32x4 v0 = *(const f32x4*)(x + base);
    f32x4 v1 = *(const f32x4*)(x + base + 4);
    float ss = 0.f;
    #pragma unroll
    for (int j = 0; j < 4; ++j) ss += v0[j]*v0[j] + v1[j]*v1[j];
    #pragma unroll
    for (int o = 1; o < 64; o <<= 1) ss += __shfl_xor(ss, o);
    __shared__ float red[4];
    if ((threadIdx.x & 63) == 0) red[threadIdx.x >> 6] = ss;
    __syncthreads();
    float tot = red[0] + red[1] + red[2] + red[3];
    float inv = rsqrtf(tot * (1.0f/DD) + 1e-6f);
    f32x4 w0 = *(const f32x4*)(Wt + base);
    f32x4 w1 = *(const f32x4*)(Wt + base + 4);
    u16* ob = Ob + (size_t)t*DD + base;
    float* of = Of + (size_t)t*DD + base;
    #pragma unroll
    for (int j = 0; j < 4; ++j) {
        float y0 = v0[j]*inv*w0[j];
        float y1 = v1[j]*inv*w1[j];
        ob[j] = f2b(y0); ob[4+j] = f2b(y1);
        of[j] = y0;      of[4+j] = y1;
    }
}

// ------- High-precision GEMM: C = (Ah+Al) @ (Wh+Wl), 3-term split-bf16 ------
// EPI 1: f32 store + residual; 2: f32 store
template<int EPI>
__global__ __launch_bounds__(256) void k_gemm_hi(
    const u16* __restrict__ Ah, const u16* __restrict__ Al,
    const float* __restrict__ W, float* __restrict__ C,
    const float* __restrict__ Res, int M, int N, int K)
{
    __shared__ u16 Ash[128][40];
    __shared__ u16 Asl[128][40];
    __shared__ u16 Bsh[128][40];
    __shared__ u16 Bsl[128][40];
    const int tid = threadIdx.x;
    const int lane = tid & 63;
    const int w = tid >> 6;
    const int m0 = blockIdx.y * 128, n0 = blockIdx.x * 128;
    const int wm = (w >> 1) * 64, wn = (w & 1) * 64;
    const int l15 = lane & 15, lhi = lane >> 4;
    f32x4 acc[4][4];
    #pragma unroll
    for (int a = 0; a < 4; ++a)
        #pragma unroll
        for (int b = 0; b < 4; ++b) acc[a][b] = 0;

    const int sar = tid >> 1, sac = (tid & 1) * 16;
    const int skk = tid >> 5, sn4 = (tid & 31) * 4;

    for (int k0 = 0; k0 < K; k0 += 32) {
        __syncthreads();
        {
            const u16* aph = Ah + (size_t)(m0 + sar) * K + k0 + sac;
            const u16* apl = Al + (size_t)(m0 + sar) * K + k0 + sac;
            *(short8*)&Ash[sar][sac]     = *(const short8*)aph;
            *(short8*)&Ash[sar][sac + 8] = *(const short8*)(aph + 8);
            *(short8*)&Asl[sar][sac]     = *(const short8*)apl;
            *(short8*)&Asl[sar][sac + 8] = *(const short8*)(apl + 8);
        }
        #pragma unroll
        for (int p = 0; p < 4; ++p) {
            int kr = p * 8 + skk;
            f32x4 wv = *(const f32x4*)(W + (size_t)(k0 + kr) * N + n0 + sn4);
            #pragma unroll
            for (int j = 0; j < 4; ++j) {
                u16 hb = f2b(wv[j]);
                Bsh[sn4 + j][kr] = hb;
                Bsl[sn4 + j][kr] = f2b(wv[j] - b2f(hb));
            }
        }
        __syncthreads();
        short8 afh[4], afl[4], bfh[4], bfl[4];
        #pragma unroll
        for (int i = 0; i < 4; ++i) {
            afh[i] = *(const short8*)&Ash[wm + i*16 + l15][lhi*8];
            afl[i] = *(const short8*)&Asl[wm + i*16 + l15][lhi*8];
            bfh[i] = *(const short8*)&Bsh[wn + i*16 + l15][lhi*8];
            bfl[i] = *(const short8*)&Bsl[wn + i*16 + l15][lhi*8];
        }
        #pragma unroll
        for (int a = 0; a < 4; ++a)
            #pragma unroll
            for (int b = 0; b < 4; ++b) {
                acc[a][b] = MFMA_16x16x32(afh[a], bfh[b], acc[a][b]);
                acc[a][b] = MFMA_16x16x32(afh[a], bfl[b], acc[a][b]);
                acc[a][b] = MFMA_16x16x32(afl[a], bfh[b], acc[a][b]);
            }
    }
    #pragma unroll
    for (int a = 0; a < 4; ++a)
      #pragma unroll
      for (int b = 0; b < 4; ++b)
        #pragma unroll
        for (int r = 0; r < 4; ++r) {
            int m = m0 + wm + a*16 + lhi*4 + r;
            int n = n0 + wn + b*16 + l15;
            size_t off = (size_t)m * N + n;
            float v = acc[a][b][r];
            if (EPI == 1) C[off] = v + Res[off];
            else C[off] = v;
        }
}

// ---------------- Dense GEMM: C(MxN) = A_bf16(MxK) @ W_f32(KxN) -------------
// EPI 0: bf16 store; 2: f32 store
template<int EPI>
__global__ __launch_bounds__(256) void k_gemm(
    const u16* __restrict__ A, const float* __restrict__ W,
    void* __restrict__ C, int M, int N, int K)
{
    __shared__ u16 As[128][40];
    __shared__ u16 Bs[128][40];
    const int tid = threadIdx.x;
    const int lane = tid & 63;
    const int w = tid >> 6;
    const int m0 = blockIdx.y * 128, n0 = blockIdx.x * 128;
    const int wm = (w >> 1) * 64, wn = (w & 1) * 64;
    const int l15 = lane & 15, lhi = lane >> 4;
    f32x4 acc[4][4];
    #pragma unroll
    for (int a = 0; a < 4; ++a)
        #pragma unroll
        for (int b = 0; b < 4; ++b) acc[a][b] = 0;

    const int sar = tid >> 1, sac = (tid & 1) * 16;
    const int skk = tid >> 5, sn4 = (tid & 31) * 4;

    for (int k0 = 0; k0 < K; k0 += 32) {
        __syncthreads();
        {
            const u16* ap = A + (size_t)(m0 + sar) * K + k0 + sac;
            *(short8*)&As[sar][sac]     = *(const short8*)ap;
            *(short8*)&As[sar][sac + 8] = *(const short8*)(ap + 8);
        }
        #pragma unroll
        for (int p = 0; p < 4; ++p) {
            int kr = p * 8 + skk;
            f32x4 wv = *(const f32x4*)(W + (size_t)(k0 + kr) * N + n0 + sn4);
            Bs[sn4 + 0][kr] = f2b(wv[0]);
            Bs[sn4 + 1][kr] = f2b(wv[1]);
            Bs[sn4 + 2][kr] = f2b(wv[2]);
            Bs[sn4 + 3][kr] = f2b(wv[3]);
        }
        __syncthreads();
        short8 af[4], bf[4];
        #pragma unroll
        for (int i = 0; i < 4; ++i) af[i] = *(const short8*)&As[wm + i*16 + l15][lhi*8];
        #pragma unroll
        for (int i = 0; i < 4; ++i) bf[i] = *(const short8*)&Bs[wn + i*16 + l15][lhi*8];
        #pragma unroll
        for (int a = 0; a < 4; ++a)
            #pragma unroll
            for (int b = 0; b < 4; ++b)
                acc[a][b] = MFMA_16x16x32(af[a], bf[b], acc[a][b]);
    }
    #pragma unroll
    for (int a = 0; a < 4; ++a)
      #pragma unroll
      for (int b = 0; b < 4; ++b)
        #pragma unroll
        for (int r = 0; r < 4; ++r) {
            int m = m0 + wm + a*16 + lhi*4 + r;
            int n = n0 + wn + b*16 + l15;
            size_t off = (size_t)m * N + n;
            float v = acc[a][b][r];
            if (EPI == 0) ((u16*)C)[off] = f2b(v);
            else ((float*)C)[off] = v;
        }
}

// ---------------- Fused GLU GEMM: h = silu(A@W1) * (A@W2), bf16 out ---------
template<bool GATHER>
__global__ __launch_bounds__(256) void k_glu(
    const u16* __restrict__ Xb, const float* __restrict__ W1,
    const float* __restrict__ W2, u16* __restrict__ Hout,
    const int* __restrict__ list, const int* __restrict__ cntp,
    int M, int NE, int K)
{
    const int e = GATHER ? blockIdx.z : 0;
    const int cnt = GATHER ? cntp[e] : M;
    const int m0 = blockIdx.y * 128;
    if (m0 >= cnt) return;
    const int n0 = blockIdx.x * 64;
    const float* w1 = W1 + (size_t)e * K * NE;
    const float* w2 = W2 + (size_t)e * K * NE;
    u16* hout = Hout + (size_t)e * CAP * NE;
    const int* lst = GATHER ? (list + e * CAP) : nullptr;

    __shared__ u16 As[128][40];
    __shared__ u16 B1s[64][40];
    __shared__ u16 B2s[64][40];

    const int tid = threadIdx.x, lane = tid & 63, w = tid >> 6;
    const int wm = (w >> 1) * 64, wn = (w & 1) * 32;
    const int l15 = lane & 15, lhi = lane >> 4;
    f32x4 acc1[4][2], acc2[4][2];
    #pragma unroll
    for (int a = 0; a < 4; ++a)
        #pragma unroll
        for (int j = 0; j < 2; ++j) { acc1[a][j] = 0; acc2[a][j] = 0; }

    const int sar = tid >> 1, sac = (tid & 1) * 16;
    int arow;
    if (GATHER) {
        int mrow = m0 + sar;
        arow = (mrow < cnt) ? (lst[mrow] >> 3) : 0;
    } else arow = m0 + sar;
    const int skk = tid >> 4;          // 0..15
    const int sn4 = (tid & 15) * 4;    // 0..60

    for (int k0 = 0; k0 < K; k0 += 32) {
        __syncthreads();
        {
            const u16* ap = Xb + (size_t)arow * K + k0 + sac;
            *(short8*)&As[sar][sac]     = *(const short8*)ap;
            *(short8*)&As[sar][sac + 8] = *(const short8*)(ap + 8);
        }
        #pragma unroll
        for (int p = 0; p < 2; ++p) {
            int kr = p * 16 + skk;
            f32x4 a1 = *(const f32x4*)(w1 + (size_t)(k0+kr)*NE + n0 + sn4);
            f32x4 a2 = *(const f32x4*)(w2 + (size_t)(k0+kr)*NE + n0 + sn4);
            #pragma unroll
            for (int j = 0; j < 4; ++j) {
                B1s[sn4 + j][kr] = f2b(a1[j]);
                B2s[sn4 + j][kr] = f2b(a2[j]);
            }
        }
        __syncthreads();
        short8 af[4], b1[2], b2[2];
        #pragma unroll
        for (int i = 0; i < 4; ++i) af[i] = *(const short8*)&As[wm + i*16 + l15][lhi*8];
        #pragma unroll
        for (int j = 0; j < 2; ++j) {
            b1[j] = *(const short8*)&B1s[wn + j*16 + l15][lhi*8];
            b2[j] = *(const short8*)&B2s[wn + j*16 + l15][lhi*8];
        }
        #pragma unroll
        for (int a = 0; a < 4; ++a)
            #pragma unroll
            for (int j = 0; j < 2; ++j) {
                acc1[a][j] = MFMA_16x16x32(af[a], b1[j], acc1[a][j]);
                acc2[a][j] = MFMA_16x16x32(af[a], b2[j], acc2[a][j]);
            }
    }
    #pragma unroll
    for (int a = 0; a < 4; ++a)
      #pragma unroll
      for (int j = 0; j < 2; ++j)
        #pragma unroll
        for (int r = 0; r < 4; ++r) {
            int m = m0 + wm + a*16 + lhi*4 + r;
            if (m < cnt) {
                int n = n0 + wn + j*16 + l15;
                float g = acc1[a][j][r], u = acc2[a][j][r];
                float hval = g / (1.0f + __expf(-g)) * u;
                hout[(size_t)m * NE + n] = f2b(hval);
            }
        }
}

// ---------------- Routed down GEMM with scatter + weight --------------------
__global__ __launch_bounds__(256) void k_down_scatter(
    const u16* __restrict__ Hb, const float* __restrict__ Wd,
    u16* __restrict__ Rbuf, const int* __restrict__ list,
    const float* __restrict__ wts, const int* __restrict__ cntp,
    int N, int K)
{
    const int e = blockIdx.z;
    const int cnt = cntp[e];
    const int m0 = blockIdx.y * 128;
    if (m0 >= cnt) return;
    const int n0 = blockIdx.x * 128;
    const u16* A = Hb + (size_t)e * CAP * K;
    const float* W = Wd + (size_t)e * K * N;

    __shared__ u16 As[128][40];
    __shared__ u16 Bs[128][40];
    const int tid = threadIdx.x, lane = tid & 63, w = tid >> 6;
    const int wm = (w >> 1) * 64, wn = (w & 1) * 64;
    const int l15 = lane & 15, lhi = lane >> 4;
    f32x4 acc[4][4];
    #pragma unroll
    for (int a = 0; a < 4; ++a)
        #pragma unroll
        for (int b = 0; b < 4; ++b) acc[a][b] = 0;

    const int sar = tid >> 1, sac = (tid & 1) * 16;
    const int skk = tid >> 5, sn4 = (tid & 31) * 4;

    for (int k0 = 0; k0 < K; k0 += 32) {
        __syncthreads();
        {
            const u16* ap = A + (size_t)(m0 + sar) * K + k0 + sac;
            *(short8*)&As[sar][sac]     = *(const short8*)ap;
            *(short8*)&As[sar][sac + 8] = *(const short8*)(ap + 8);
        }
        #pragma unroll
        for (int p = 0; p < 4; ++p) {
            int kr = p * 8 + skk;
            f32x4 wv = *(const f32x4*)(W + (size_t)(k0 + kr) * N + n0 + sn4);
            Bs[sn4 + 0][kr] = f2b(wv[0]);
            Bs[sn4 + 1][kr] = f2b(wv[1]);
            Bs[sn4 + 2][kr] = f2b(wv[2]);
            Bs[sn4 + 3][kr] = f2b(wv[3]);
        }
        __syncthreads();
        short8 af[4], bf[4];
        #pragma unroll
        for (int i = 0; i < 4; ++i) af[i] = *(const short8*)&As[wm + i*16 + l15][lhi*8];
        #pragma unroll
        for (int i = 0; i < 4; ++i) bf[i] = *(const short8*)&Bs[wn + i*16 + l15][lhi*8];
        #pragma unroll
        for (int a = 0; a < 4; ++a)
            #pragma unroll
            for (int b = 0; b < 4; ++b)
                acc[a][b] = MFMA_16x16x32(af[a], bf[b], acc[a][b]);
    }
    #pragma unroll
    for (int a = 0; a < 4; ++a)
      #pragma unroll
      for (int b = 0; b < 4; ++b)
        #pragma unroll
        for (int r = 0; r < 4; ++r) {
            int m = m0 + wm + a*16 + lhi*4 + r;
            if (m < cnt) {
                int n = n0 + wn + b*16 + l15;
                int enc = list[e*CAP + m];
                float wgt = wts[e*CAP + m];
                int tok = enc >> 3, kk = enc & 7;
                Rbuf[((size_t)tok*NTOP + kk)*N + n] = f2b(acc[a][b][r] * wgt);
            }
        }
}

// ---------------- RoPE in-place on f32 q and k ------------------------------
__global__ __launch_bounds__(256) void k_rope_f32(
    float* __restrict__ Qf, float* __restrict__ Kf,
    const float* __restrict__ Cs, const float* __restrict__ Sn)
{
    int id = blockIdx.x * 256 + threadIdx.x;   // TT * 20 * 64
    int pr = id & 63;
    int rest = id >> 6;
    int hh = rest % 20;
    int tok = rest / 20;
    if (tok >= TT) return;
    int d0 = pr * 2;
    float c0 = Cs[(size_t)tok*HDD + d0];
    float c1 = Cs[(size_t)tok*HDD + d0 + 1];
    float s0 = Sn[(size_t)tok*HDD + d0];
    float s1 = Sn[(size_t)tok*HDD + d0 + 1];
    float* p = (hh < HH) ? (Qf + ((size_t)tok*HH + hh)*HDD)
                         : (Kf + ((size_t)tok*HKK + (hh - HH))*HDD);
    float x0 = p[d0], x1 = p[d0+1];
    p[d0]     = x0*c0 - x1*s0;
    p[d0 + 1] = x1*c1 + x0*s1;
}

// ---------------- Split f32 buffer into (hi,lo) bf16 ------------------------
__global__ __launch_bounds__(256) void k_split(
    const float* __restrict__ X, u16* __restrict__ Hi, u16* __restrict__ Lo, int n)
{
    int id = blockIdx.x * 256 + threadIdx.x;
    int base = id * 8;
    if (base >= n) return;
    f32x4 v0 = *(const f32x4*)(X + base);
    f32x4 v1 = *(const f32x4*)(X + base + 4);
    u16* h = Hi + base; u16* l = Lo + base;
    #pragma unroll
    for (int j = 0; j < 4; ++j) {
        fsplit(v0[j], h[j],   l[j]);
        fsplit(v1[j], h[4+j], l[4+j]);
    }
}

// ---------------- V f32 (b,s,hk,d) -> split V^T (b,hk,d,s) ------------------
__global__ __launch_bounds__(256) void k_split_vt(
    const float* __restrict__ Vf, u16* __restrict__ Vth, u16* __restrict__ Vtl)
{
    int id = blockIdx.x * 256 + threadIdx.x;   // TT*HKK*HDD/8
    int oid = id * 8;
    int s0 = oid & (SS - 1);
    int r = oid >> 10;
    int d = r & (HDD - 1);
    int bh = r >> 7;
    int b = bh >> 2, hk = bh & 3;
    #pragma unroll
    for (int j = 0; j < 8; ++j) {
        int s = s0 + j;
        float v = Vf[((size_t)(b*SS + s)*HKK + hk)*HDD + d];
        fsplit(v, Vth[oid + j], Vtl[oid + j]);
    }
}

// ---------------- Flash attention, split-bf16 precision ---------------------
__global__ __launch_bounds__(256) void k_attn_hi(
    const u16* __restrict__ Qh, const u16* __restrict__ Ql,
    const u16* __restrict__ Kh, const u16* __restrict__ Kl,
    const u16* __restrict__ Vth, const u16* __restrict__ Vtl,
    u16* __restrict__ Oh, u16* __restrict__ Ol)
{
    const int tid = threadIdx.x;
    const int lane = tid & 63;
    const int w = tid >> 6;
    const int q0 = blockIdx.x * 64;
    const int b = blockIdx.y >> 4;
    const int h = blockIdx.y & 15;
    const int hk = h >> 2;
    const int l15 = lane & 15, lhi = lane >> 4;

    __shared__ u16 Ksh[32][136];
    __shared__ u16 Ksl[32][136];
    __shared__ u16 Vsh[128][40];
    __shared__ u16 Vsl[128][40];
    __shared__ u16 Psh[4][16][40];
    __shared__ u16 Psl[4][16][40];

    short8 qfh[4], qfl[4];
    {
        const int qrow = q0 + w*16 + l15;
        const u16* qph = Qh + ((size_t)(b*SS + qrow)*HH + h)*HDD;
        const u16* qpl = Ql + ((size_t)(b*SS + qrow)*HH + h)*HDD;
        #pragma unroll
        for (int c = 0; c < 4; ++c) {
            qfh[c] = *(const short8*)(qph + c*32 + lhi*8);
            qfl[c] = *(const short8*)(qpl + c*32 + lhi*8);
        }
    }

    f32x4 oacc[8];
    #pragma unroll
    for (int ch = 0; ch < 8; ++ch) oacc[ch] = 0;
    float m_r[4] = {-1e30f, -1e30f, -1e30f, -1e30f};
    float l_r[4] = {0.f, 0.f, 0.f, 0.f};

    const int nkt = (q0 + 64) >> 5;
    const int kr = tid >> 3, kc = (tid & 7) * 16;
    const int vd = tid >> 1, vj = (tid & 1) * 16;

    for (int kt = 0; kt < nkt; ++kt) {
        __syncthreads();
        {
            size_t koff = ((size_t)(b*SS + kt*32 + kr)*HKK + hk)*HDD + kc;
            *(short8*)&Ksh[kr][kc]     = *(const short8*)(Kh + koff);
            *(short8*)&Ksh[kr][kc + 8] = *(const short8*)(Kh + koff + 8);
            *(short8*)&Ksl[kr][kc]     = *(const short8*)(Kl + koff);
            *(short8*)&Ksl[kr][kc + 8] = *(const short8*)(Kl + koff + 8);
        }
        {
            size_t voff = ((size_t)(b*HKK + hk)*HDD + vd)*SS + kt*32 + vj;
            *(short8*)&Vsh[vd][vj]     = *(const short8*)(Vth + voff);
            *(short8*)&Vsh[vd][vj + 8] = *(const short8*)(Vth + voff + 8);
            *(short8*)&Vsl[vd][vj]     = *(const short8*)(Vtl + voff);
            *(short8*)&Vsl[vd][vj + 8] = *(const short8*)(Vtl + voff + 8);
        }
        __syncthreads();

        f32x4 s0 = 0, s1 = 0;
        #pragma unroll
        for (int c = 0; c < 4; ++c) {
            short8 kh0 = *(const short8*)&Ksh[l15][c*32 + lhi*8];
            short8 kl0 = *(const short8*)&Ksl[l15][c*32 + lhi*8];
            short8 kh1 = *(const short8*)&Ksh[16 + l15][c*32 + lhi*8];
            short8 kl1 = *(const short8*)&Ksl[16 + l15][c*32 + lhi*8];
            s0 = MFMA_16x16x32(qfh[c], kh0, s0);
            s0 = MFMA_16x16x32(qfh[c], kl0, s0);
            s0 = MFMA_16x16x32(qfl[c], kh0, s0);
            s1 = MFMA_16x16x32(qfh[c], kh1, s1);
            s1 = MFMA_16x16x32(qfh[c], kl1, s1);
            s1 = MFMA_16x16x32(qfl[c], kh1, s1);
        }
        const int irow0 = q0 + w*16 + lhi*4;
        const int j0 = kt*32 + l15;
        float ef[4];
        #pragma unroll
        for (int r = 0; r < 4; ++r) {
            float a0 = s0[r] * 0.08838834764831845f;
            float a1 = s1[r] * 0.08838834764831845f;
            const int ir = irow0 + r;
            if (j0 > ir) a0 = -1e30f;
            if (j0 + 16 > ir) a1 = -1e30f;
            float mx = fmaxf(a0, a1);
            #pragma unroll
            for (int o = 1; o < 16; o <<= 1) mx = fmaxf(mx, __shfl_xor(mx, o));
            float mn = fmaxf(m_r[r], mx);
            ef[r] = __expf(m_r[r] - mn);
            m_r[r] = mn;
            float p0 = __expf(a0 - mn);
            float p1 = __expf(a1 - mn);
            float ps = p0 + p1;
            #pragma unroll
            for (int o = 1; o < 16; o <<= 1) ps += __shfl_xor(ps, o);
            l_r[r] = l_r[r]*ef[r] + ps;
            fsplit(p0, Psh[w][lhi*4 + r][l15],      Psl[w][lhi*4 + r][l15]);
            fsplit(p1, Psh[w][lhi*4 + r][16 + l15], Psl[w][lhi*4 + r][16 + l15]);
        }
        #pragma unroll
        for (int ch = 0; ch < 8; ++ch) {
            f32x4 t = oacc[ch];
            t[0] *= ef[0]; t[1] *= ef[1]; t[2] *= ef[2]; t[3] *= ef[3];
            oacc[ch] = t;
        }
        __syncthreads();
        short8 pah = *(const short8*)&Psh[w][l15][lhi*8];
        short8 pal = *(const short8*)&Psl[w][l15][lhi*8];
        #pragma unroll
        for (int ch = 0; ch < 8; ++ch) {
            short8 bvh = *(const short8*)&Vsh[ch*16 + l15][lhi*8];
            short8 bvl = *(const short8*)&Vsl[ch*16 + l15][lhi*8];
            oacc[ch] = MFMA_16x16x32(pah, bvh, oacc[ch]);
            oacc[ch] = MFMA_16x16x32(pah, bvl, oacc[ch]);
            oacc[ch] = MFMA_16x16x32(pal, bvh, oacc[ch]);
        }
    }
    #pragma unroll
    for (int r = 0; r < 4; ++r) {
        const int row = q0 + w*16 + lhi*4 + r;
        const float inv = 1.0f / l_r[r];
        u16* oph = Oh + ((size_t)(b*SS + row)*HH + h)*HDD;
        u16* opl = Ol + ((size_t)(b*SS + row)*HH + h)*HDD;
        #pragma unroll
        for (int ch = 0; ch < 8; ++ch) {
            float o = oacc[ch][r] * inv;
            fsplit(o, oph[ch*16 + l15], opl[ch*16 + l15]);
        }
    }
}

// ---------------- Router: f32 logits, softmax, top-6, slot lists ------------
__global__ __launch_bounds__(256) void k_router(
    const float* __restrict__ X, const float* __restrict__ Wg,
    const float* __restrict__ bias,
    int* __restrict__ cnt, int* __restrict__ list, float* __restrict__ wts)
{
    const int t = blockIdx.x;
    const int e = threadIdx.x & 15, sl = threadIdx.x >> 4;
    const float* x = X + (size_t)t * DD;
    float part = 0.f;
    for (int i = 0; i < 128; ++i) {
        int k = sl * 128 + i;
        part += x[k] * Wg[(size_t)k * EE + e];
    }
    __shared__ float red[16][17];
    red[sl][e] = part;
    __syncthreads();
    if (threadIdx.x == 0) {
        float lg[16], pr[16];
        for (int ee = 0; ee < 16; ++ee) {
            float s = 0.f;
            for (int q = 0; q < 16; ++q) s += red[q][ee];
            lg[ee] = s;
        }
        float mx = lg[0];
        for (int ee = 1; ee < 16; ++ee) mx = fmaxf(mx, lg[ee]);
        float sum = 0.f;
        for (int ee = 0; ee < 16; ++ee) { pr[ee] = expf(lg[ee] - mx); sum += pr[ee]; }
        float isum = 1.0f / sum;
        for (int ee = 0; ee < 16; ++ee) pr[ee] *= isum;
        unsigned used = 0;
        int sel[NTOP]; float rw[NTOP]; float s6 = 0.f;
        for (int kk = 0; kk < NTOP; ++kk) {
            int best = 0; float bv = -1e30f;
            for (int ee = 0; ee < 16; ++ee) {
                if (used & (1u << ee)) continue;
                float sc = pr[ee] + bias[ee];
                if (sc > bv) { bv = sc; best = ee; }
            }
            used |= 1u << best;
            sel[kk] = best; rw[kk] = pr[best]; s6 += pr[best];
        }
        float inv6 = 1.0f / fmaxf(s6, 1e-12f);
        for (int kk = 0; kk < NTOP; ++kk) {
            int ee = sel[kk];
            int pos = atomicAdd(&cnt[ee], 1);
            list[ee*CAP + pos] = (t << 3) | kk;
            wts[ee*CAP + pos] = rw[kk] * inv6;
        }
    }
}

// ---------------- Final: out = h2 + shared + sum_kk routed ------------------
__global__ __launch_bounds__(256) void k_final(
    const float* __restrict__ h2, const float* __restrict__ yb,
    const u16* __restrict__ rb, float* __restrict__ out)
{
    int id = blockIdx.x * 256 + threadIdx.x;     // T*D/4
    size_t i4 = (size_t)id * 4;
    int t = id >> 9;
    int d = (id & 511) * 4;
    f32x4 acc = *(const f32x4*)(h2 + i4);
    f32x4 y = *(const f32x4*)(yb + i4);
    acc += y;
    #pragma unroll
    for (int kk = 0; kk < NTOP; ++kk) {
        const u16* rp = rb + ((size_t)t*NTOP + kk)*DD + d;
        acc[0] += b2f(rp[0]); acc[1] += b2f(rp[1]);
        acc[2] += b2f(rp[2]); acc[3] += b2f(rp[3]);
    }
    *(f32x4*)(out + i4) = acc;
}

extern "C" void kernel_launch(void* const* d_in, const int* in_sizes, int n_in,
                              void* d_out, int out_size, void* d_ws, size_t ws_size,
                              hipStream_t stream)
{
    (void)in_sizes; (void)n_in; (void)out_size; (void)ws_size;
    const float* hidden = (const float*)d_in[0];
    const float* cosb   = (const float*)d_in[1];
    const float* sinb   = (const float*)d_in[2];
    const float* ln1    = (const float*)d_in[3];
    const float* ln2    = (const float*)d_in[4];
    const float* Wq     = (const float*)d_in[5];
    const float* Wk     = (const float*)d_in[6];
    const float* Wv     = (const float*)d_in[7];
    const float* Wo     = (const float*)d_in[8];
    const float* Wgate  = (const float*)d_in[9];
    const float* cbias  = (const float*)d_in[10];
    const float* Wg     = (const float*)d_in[11];
    const float* Wu     = (const float*)d_in[12];
    const float* Wd     = (const float*)d_in[13];
    const float* Wgs    = (const float*)d_in[14];
    const float* Wus    = (const float*)d_in[15];
    const float* Wds    = (const float*)d_in[16];
    float* out = (float*)d_out;

    char* ws = (char*)d_ws;
    size_t off = 0;
    auto alloc = [&](size_t bytes) {
        void* p = ws + off;
        off = (off + bytes + 255) & ~(size_t)255;
        return p;
    };
    u16*   x1h  = (u16*)  alloc((size_t)TT*DD*2);
    u16*   x1l  = (u16*)  alloc((size_t)TT*DD*2);
    float* qf   = (float*)alloc((size_t)TT*HH*HDD*4);
    float* kf   = (float*)alloc((size_t)TT*HKK*HDD*4);
    float* vf   = (float*)alloc((size_t)TT*HKK*HDD*4);
    u16*   qh   = (u16*)  alloc((size_t)TT*HH*HDD*2);
    u16*   ql   = (u16*)  alloc((size_t)TT*HH*HDD*2);
    u16*   kh   = (u16*)  alloc((size_t)TT*HKK*HDD*2);
    u16*   kl   = (u16*)  alloc((size_t)TT*HKK*HDD*2);
    u16*   vth  = (u16*)  alloc((size_t)TT*HKK*HDD*2);
    u16*   vtl  = (u16*)  alloc((size_t)TT*HKK*HDD*2);
    u16*   aoh  = (u16*)  alloc((size_t)TT*HH*HDD*2);
    u16*   aol  = (u16*)  alloc((size_t)TT*HH*HDD*2);
    float* h2   = (float*)alloc((size_t)TT*DD*4);
    u16*   x2   = (u16*)  alloc((size_t)TT*DD*2);
    float* x2f  = (float*)alloc((size_t)TT*DD*4);
    int*   cnt  = (int*)  alloc(256);
    int*   lst  = (int*)  alloc((size_t)EE*CAP*4);
    float* wts  = (float*)alloc((size_t)EE*CAP*4);
    u16*   hs   = (u16*)  alloc((size_t)TT*ISS*2);
    u16*   hE   = (u16*)  alloc((size_t)EE*CAP*II*2);
    float* ybuf = (float*)alloc((size_t)TT*DD*4);
    u16*   rbuf = (u16*)  alloc((size_t)TT*NTOP*DD*2);

    k_rmsnorm_split<<<TT, 256, 0, stream>>>(hidden, ln1, x1h, x1l);
    k_gemm_hi<2><<<dim3(16,16), 256, 0, stream>>>(x1h, x1l, Wq, qf, nullptr, TT, HH*HDD, DD);
    k_gemm_hi<2><<<dim3(4,16),  256, 0, stream>>>(x1h, x1l, Wk, kf, nullptr, TT, HKK*HDD, DD);
    k_gemm_hi<2><<<dim3(4,16),  256, 0, stream>>>(x1h, x1l, Wv, vf, nullptr, TT, HKK*HDD, DD);
    k_rope_f32<<<(TT*20*64)/256, 256, 0, stream>>>(qf, kf, cosb, sinb);
    k_split<<<(TT*HH*HDD/8)/256, 256, 0, stream>>>(qf, qh, ql, TT*HH*HDD);
    k_split<<<(TT*HKK*HDD/8)/256, 256, 0, stream>>>(kf, kh, kl, TT*HKK*HDD);
    k_split_vt<<<(TT*HKK*HDD/8)/256, 256, 0, stream>>>(vf, vth, vtl);
    k_attn_hi<<<dim3(SS/64, BB*HH), 256, 0, stream>>>(qh, ql, kh, kl, vth, vtl, aoh, aol);
    k_gemm_hi<1><<<dim3(16,16), 256, 0, stream>>>(aoh, aol, Wo, h2, hidden, TT, DD, HH*HDD);
    k_rmsnorm_bf<<<TT, 256, 0, stream>>>(h2, ln2, x2, x2f);
    hipMemsetAsync(cnt, 0, 256, stream);
    k_router<<<TT, 256, 0, stream>>>(x2f, Wgate, cbias, cnt, lst, wts);
    k_glu<false><<<dim3(ISS/64, TT/128, 1), 256, 0, stream>>>(x2, Wgs, Wus, hs, nullptr, nullptr, TT, ISS, DD);
    k_gemm<2><<<dim3(16,16), 256, 0, stream>>>(hs, Wds, ybuf, TT, DD, ISS);
    k_glu<true><<<dim3(II/64, CAP/128, EE), 256, 0, stream>>>(x2, Wg, Wu, hE, lst, cnt, CAP, II, DD);
    k_down_scatter<<<dim3(DD/128, CAP/128, EE), 256, 0, stream>>>(hE, Wd, rbuf, lst, wts, cnt, DD, II);
    k_final<<<(TT*DD/4)/256, 256, 0, stream>>>(h2, ybuf, rbuf, out);
}

// Round 4
// 1142.235 us; speedup vs baseline: 1.7502x; 1.7502x over previous
//
#include <hip/hip_runtime.h>
#include <cstdint>

typedef unsigned short u16;
typedef __attribute__((ext_vector_type(8))) short short8;
typedef __attribute__((ext_vector_type(4))) short s16x4;
typedef __attribute__((ext_vector_type(4))) float f32x4;

#define MFMA_16x16x32(a,b,c) __builtin_amdgcn_mfma_f32_16x16x32_bf16(a,b,c,0,0,0)

#define BB 2
#define SS 1024
#define DD 2048
#define HH 16
#define HKK 4
#define HDD 128
#define EE 16
#define NTOP 6
#define II 1024
#define ISS 2048
#define TT 2048
#define CAP 2048

__device__ __forceinline__ u16 f2b(float f) {
    union { float f; uint32_t u; } v; v.f = f;
    uint32_t r = v.u + 0x7FFFu + ((v.u >> 16) & 1u);
    return (u16)(r >> 16);
}
__device__ __forceinline__ float b2f(u16 h) {
    union { uint32_t u; float f; } v; v.u = ((uint32_t)h) << 16;
    return v.f;
}
__device__ __forceinline__ void fsplit(float f, u16& hi, u16& lo) {
    u16 h = f2b(f);
    hi = h;
    lo = f2b(f - b2f(h));
}

// ---------- Prep: transpose+convert W f32 [R][C] -> bf16 [C][R] (hi[,lo]) ---
template<bool SPLIT>
__global__ __launch_bounds__(256) void k_prep(
    const float* __restrict__ In, u16* __restrict__ Oh, u16* __restrict__ Ol,
    int R, int C)
{
    const size_t zoff = (size_t)blockIdx.z * R * C;
    In += zoff; Oh += zoff; if (SPLIT) Ol += zoff;
    const int r0 = blockIdx.y * 32, c0 = blockIdx.x * 32;
    __shared__ float tile[32][33];
    const int tx = threadIdx.x & 31, ty = threadIdx.x >> 5;
    #pragma unroll
    for (int i = 0; i < 4; ++i)
        tile[ty + i*8][tx] = In[(size_t)(r0 + ty + i*8)*C + c0 + tx];
    __syncthreads();
    const int c = threadIdx.x >> 3, rs = (threadIdx.x & 7) * 4;
    s16x4 hv, lv;
    #pragma unroll
    for (int j = 0; j < 4; ++j) {
        float f = tile[rs + j][c];
        u16 hb = f2b(f);
        hv[j] = (short)hb;
        if (SPLIT) lv[j] = (short)f2b(f - b2f(hb));
        else lv[j] = 0;
    }
    *(s16x4*)(Oh + (size_t)(c0 + c)*R + r0 + rs) = hv;
    if (SPLIT) *(s16x4*)(Ol + (size_t)(c0 + c)*R + r0 + rs) = lv;
}

// ---------------- RMSNorm f32 in -> split bf16 (hi,lo) ----------------------
__global__ __launch_bounds__(256) void k_rmsnorm_split(
    const float* __restrict__ X, const float* __restrict__ Wt,
    u16* __restrict__ Oh, u16* __restrict__ Ol)
{
    const int t = blockIdx.x;
    const float* x = X + (size_t)t * DD;
    const int base = threadIdx.x * 8;
    f32x4 v0 = *(const f32x4*)(x + base);
    f32x4 v1 = *(const f32x4*)(x + base + 4);
    float ss = 0.f;
    #pragma unroll
    for (int j = 0; j < 4; ++j) ss += v0[j]*v0[j] + v1[j]*v1[j];
    #pragma unroll
    for (int o = 1; o < 64; o <<= 1) ss += __shfl_xor(ss, o);
    __shared__ float red[4];
    if ((threadIdx.x & 63) == 0) red[threadIdx.x >> 6] = ss;
    __syncthreads();
    float tot = red[0] + red[1] + red[2] + red[3];
    float inv = rsqrtf(tot * (1.0f/DD) + 1e-6f);
    f32x4 w0 = *(const f32x4*)(Wt + base);
    f32x4 w1 = *(const f32x4*)(Wt + base + 4);
    u16* oh = Oh + (size_t)t*DD + base;
    u16* ol = Ol + (size_t)t*DD + base;
    #pragma unroll
    for (int j = 0; j < 4; ++j) {
        float y0 = v0[j]*inv*w0[j];
        float y1 = v1[j]*inv*w1[j];
        fsplit(y0, oh[j],   ol[j]);
        fsplit(y1, oh[4+j], ol[4+j]);
    }
}

// ---------------- RMSNorm f32 in -> bf16 + f32 ------------------------------
__global__ __launch_bounds__(256) void k_rmsnorm_bf(
    const float* __restrict__ X, const float* __restrict__ Wt,
    u16* __restrict__ Ob, float* __restrict__ Of)
{
    const int t = blockIdx.x;
    const float* x = X + (size_t)t * DD;
    const int base = threadIdx.x * 8;
    f32x4 v0 = *(const f32x4*)(x + base);
    f32x4 v1 = *(const f32x4*)(x + base + 4);
    float ss = 0.f;
    #pragma unroll
    for (int j = 0; j < 4; ++j) ss += v0[j]*v0[j] + v1[j]*v1[j];
    #pragma unroll
    for (int o = 1; o < 64; o <<= 1) ss += __shfl_xor(ss, o);
    __shared__ float red[4];
    if ((threadIdx.x & 63) == 0) red[threadIdx.x >> 6] = ss;
    __syncthreads();
    float tot = red[0] + red[1] + red[2] + red[3];
    float inv = rsqrtf(tot * (1.0f/DD) + 1e-6f);
    f32x4 w0 = *(const f32x4*)(Wt + base);
    f32x4 w1 = *(const f32x4*)(Wt + base + 4);
    u16* ob = Ob + (size_t)t*DD + base;
    float* of = Of + (size_t)t*DD + base;
    #pragma unroll
    for (int j = 0; j < 4; ++j) {
        float y0 = v0[j]*inv*w0[j];
        float y1 = v1[j]*inv*w1[j];
        ob[j] = f2b(y0); ob[4+j] = f2b(y1);
        of[j] = y0;      of[4+j] = y1;
    }
}

// ------- High-precision GEMM: C = (Ah+Al) @ (Bh+Bl)^T, pre-split bf16 -------
// EPI 1: f32 store + residual; 2: f32 store
template<int EPI>
__global__ __launch_bounds__(256) void k_gemm_hi(
    const u16* __restrict__ Ah, const u16* __restrict__ Al,
    const u16* __restrict__ Bth, const u16* __restrict__ Btl,
    float* __restrict__ C, const float* __restrict__ Res,
    int M, int N, int K)
{
    __shared__ u16 Ash[128][32];
    __shared__ u16 Asl[128][32];
    __shared__ u16 Bsh[128][32];
    __shared__ u16 Bsl[128][32];
    const int tid = threadIdx.x;
    const int lane = tid & 63;
    const int w = tid >> 6;
    const int m0 = blockIdx.y * 128, n0 = blockIdx.x * 128;
    const int wm = (w >> 1) * 64, wn = (w & 1) * 64;
    const int l15 = lane & 15, lhi = lane >> 4;
    f32x4 acc[4][4];
    #pragma unroll
    for (int a = 0; a < 4; ++a)
        #pragma unroll
        for (int b = 0; b < 4; ++b) acc[a][b] = 0;

    const int srow = tid >> 1, sc = (tid & 1) * 16;
    const u16* aBh = Ah  + (size_t)(m0 + srow) * K + sc;
    const u16* aBl = Al  + (size_t)(m0 + srow) * K + sc;
    const u16* bBh = Bth + (size_t)(n0 + srow) * K + sc;
    const u16* bBl = Btl + (size_t)(n0 + srow) * K + sc;

    for (int k0 = 0; k0 < K; k0 += 32) {
        __syncthreads();
        *(short8*)&Ash[srow][sc]     = *(const short8*)(aBh + k0);
        *(short8*)&Ash[srow][sc + 8] = *(const short8*)(aBh + k0 + 8);
        *(short8*)&Asl[srow][sc]     = *(const short8*)(aBl + k0);
        *(short8*)&Asl[srow][sc + 8] = *(const short8*)(aBl + k0 + 8);
        *(short8*)&Bsh[srow][sc]     = *(const short8*)(bBh + k0);
        *(short8*)&Bsh[srow][sc + 8] = *(const short8*)(bBh + k0 + 8);
        *(short8*)&Bsl[srow][sc]     = *(const short8*)(bBl + k0);
        *(short8*)&Bsl[srow][sc + 8] = *(const short8*)(bBl + k0 + 8);
        __syncthreads();
        short8 afh[4], afl[4], bfh[4], bfl[4];
        #pragma unroll
        for (int i = 0; i < 4; ++i) {
            afh[i] = *(const short8*)&Ash[wm + i*16 + l15][lhi*8];
            afl[i] = *(const short8*)&Asl[wm + i*16 + l15][lhi*8];
            bfh[i] = *(const short8*)&Bsh[wn + i*16 + l15][lhi*8];
            bfl[i] = *(const short8*)&Bsl[wn + i*16 + l15][lhi*8];
        }
        #pragma unroll
        for (int a = 0; a < 4; ++a)
            #pragma unroll
            for (int b = 0; b < 4; ++b) {
                acc[a][b] = MFMA_16x16x32(afh[a], bfh[b], acc[a][b]);
                acc[a][b] = MFMA_16x16x32(afh[a], bfl[b], acc[a][b]);
                acc[a][b] = MFMA_16x16x32(afl[a], bfh[b], acc[a][b]);
            }
    }
    #pragma unroll
    for (int a = 0; a < 4; ++a)
      #pragma unroll
      for (int b = 0; b < 4; ++b)
        #pragma unroll
        for (int r = 0; r < 4; ++r) {
            int m = m0 + wm + a*16 + lhi*4 + r;
            int n = n0 + wn + b*16 + l15;
            size_t off = (size_t)m * N + n;
            float v = acc[a][b][r];
            if (EPI == 1) C[off] = v + Res[off];
            else C[off] = v;
        }
}

// ---------------- Dense GEMM: C(MxN) = A_bf16 @ Bt_bf16^T -------------------
// EPI 0: bf16 store; 2: f32 store
template<int EPI>
__global__ __launch_bounds__(256) void k_gemm(
    const u16* __restrict__ A, const u16* __restrict__ Bt,
    void* __restrict__ C, int M, int N, int K)
{
    __shared__ u16 As[128][32];
    __shared__ u16 Bs[128][32];
    const int tid = threadIdx.x;
    const int lane = tid & 63;
    const int w = tid >> 6;
    const int m0 = blockIdx.y * 128, n0 = blockIdx.x * 128;
    const int wm = (w >> 1) * 64, wn = (w & 1) * 64;
    const int l15 = lane & 15, lhi = lane >> 4;
    f32x4 acc[4][4];
    #pragma unroll
    for (int a = 0; a < 4; ++a)
        #pragma unroll
        for (int b = 0; b < 4; ++b) acc[a][b] = 0;

    const int srow = tid >> 1, sc = (tid & 1) * 16;
    const u16* aB = A  + (size_t)(m0 + srow) * K + sc;
    const u16* bB = Bt + (size_t)(n0 + srow) * K + sc;

    for (int k0 = 0; k0 < K; k0 += 32) {
        __syncthreads();
        *(short8*)&As[srow][sc]     = *(const short8*)(aB + k0);
        *(short8*)&As[srow][sc + 8] = *(const short8*)(aB + k0 + 8);
        *(short8*)&Bs[srow][sc]     = *(const short8*)(bB + k0);
        *(short8*)&Bs[srow][sc + 8] = *(const short8*)(bB + k0 + 8);
        __syncthreads();
        short8 af[4], bf[4];
        #pragma unroll
        for (int i = 0; i < 4; ++i) af[i] = *(const short8*)&As[wm + i*16 + l15][lhi*8];
        #pragma unroll
        for (int i = 0; i < 4; ++i) bf[i] = *(const short8*)&Bs[wn + i*16 + l15][lhi*8];
        #pragma unroll
        for (int a = 0; a < 4; ++a)
            #pragma unroll
            for (int b = 0; b < 4; ++b)
                acc[a][b] = MFMA_16x16x32(af[a], bf[b], acc[a][b]);
    }
    #pragma unroll
    for (int a = 0; a < 4; ++a)
      #pragma unroll
      for (int b = 0; b < 4; ++b)
        #pragma unroll
        for (int r = 0; r < 4; ++r) {
            int m = m0 + wm + a*16 + lhi*4 + r;
            int n = n0 + wn + b*16 + l15;
            size_t off = (size_t)m * N + n;
            float v = acc[a][b][r];
            if (EPI == 0) ((u16*)C)[off] = f2b(v);
            else ((float*)C)[off] = v;
        }
}

// ---------------- Fused GLU GEMM: h = silu(A@W1) * (A@W2), bf16 out ---------
template<bool GATHER>
__global__ __launch_bounds__(256) void k_glu(
    const u16* __restrict__ Xb, const u16* __restrict__ W1t,
    const u16* __restrict__ W2t, u16* __restrict__ Hout,
    const int* __restrict__ list, const int* __restrict__ cntp,
    int M, int NE, int K)
{
    const int e = GATHER ? blockIdx.z : 0;
    const int cnt = GATHER ? cntp[e] : M;
    const int m0 = blockIdx.y * 128;
    if (m0 >= cnt) return;
    const int n0 = blockIdx.x * 64;
    const u16* w1 = W1t + (size_t)e * NE * K;
    const u16* w2 = W2t + (size_t)e * NE * K;
    u16* hout = Hout + (size_t)e * CAP * NE;
    const int* lst = GATHER ? (list + e * CAP) : nullptr;

    __shared__ u16 As[128][32];
    __shared__ u16 B1s[64][32];
    __shared__ u16 B2s[64][32];

    const int tid = threadIdx.x, lane = tid & 63, w = tid >> 6;
    const int wm = (w >> 1) * 64, wn = (w & 1) * 32;
    const int l15 = lane & 15, lhi = lane >> 4;
    f32x4 acc1[4][2], acc2[4][2];
    #pragma unroll
    for (int a = 0; a < 4; ++a)
        #pragma unroll
        for (int j = 0; j < 2; ++j) { acc1[a][j] = 0; acc2[a][j] = 0; }

    const int srow = tid >> 1, sc = (tid & 1) * 16;
    int arow;
    if (GATHER) arow = (m0 + srow < cnt) ? (lst[m0 + srow] >> 3) : 0;
    else arow = m0 + srow;
    const u16* aB = Xb + (size_t)arow * K + sc;
    const int brow = tid >> 2, bc = (tid & 3) * 8;
    const u16* b1B = w1 + (size_t)(n0 + brow) * K + bc;
    const u16* b2B = w2 + (size_t)(n0 + brow) * K + bc;

    for (int k0 = 0; k0 < K; k0 += 32) {
        __syncthreads();
        *(short8*)&As[srow][sc]     = *(const short8*)(aB + k0);
        *(short8*)&As[srow][sc + 8] = *(const short8*)(aB + k0 + 8);
        *(short8*)&B1s[brow][bc]    = *(const short8*)(b1B + k0);
        *(short8*)&B2s[brow][bc]    = *(const short8*)(b2B + k0);
        __syncthreads();
        short8 af[4], b1[2], b2[2];
        #pragma unroll
        for (int i = 0; i < 4; ++i) af[i] = *(const short8*)&As[wm + i*16 + l15][lhi*8];
        #pragma unroll
        for (int j = 0; j < 2; ++j) {
            b1[j] = *(const short8*)&B1s[wn + j*16 + l15][lhi*8];
            b2[j] = *(const short8*)&B2s[wn + j*16 + l15][lhi*8];
        }
        #pragma unroll
        for (int a = 0; a < 4; ++a)
            #pragma unroll
            for (int j = 0; j < 2; ++j) {
                acc1[a][j] = MFMA_16x16x32(af[a], b1[j], acc1[a][j]);
                acc2[a][j] = MFMA_16x16x32(af[a], b2[j], acc2[a][j]);
            }
    }
    #pragma unroll
    for (int a = 0; a < 4; ++a)
      #pragma unroll
      for (int j = 0; j < 2; ++j)
        #pragma unroll
        for (int r = 0; r < 4; ++r) {
            int m = m0 + wm + a*16 + lhi*4 + r;
            if (m < cnt) {
                int n = n0 + wn + j*16 + l15;
                float g = acc1[a][j][r], u = acc2[a][j][r];
                float hval = g / (1.0f + __expf(-g)) * u;
                hout[(size_t)m * NE + n] = f2b(hval);
            }
        }
}

// ---------------- Routed down GEMM with scatter + weight --------------------
__global__ __launch_bounds__(256) void k_down_scatter(
    const u16* __restrict__ Hb, const u16* __restrict__ WdTt,
    u16* __restrict__ Rbuf, const int* __restrict__ list,
    const float* __restrict__ wts, const int* __restrict__ cntp,
    int N, int K)
{
    const int e = blockIdx.z;
    const int cnt = cntp[e];
    const int m0 = blockIdx.y * 128;
    if (m0 >= cnt) return;
    const int n0 = blockIdx.x * 128;
    const u16* A  = Hb   + (size_t)e * CAP * K;
    const u16* Bt = WdTt + (size_t)e * N * K;

    __shared__ u16 As[128][32];
    __shared__ u16 Bs[128][32];
    const int tid = threadIdx.x, lane = tid & 63, w = tid >> 6;
    const int wm = (w >> 1) * 64, wn = (w & 1) * 64;
    const int l15 = lane & 15, lhi = lane >> 4;
    f32x4 acc[4][4];
    #pragma unroll
    for (int a = 0; a < 4; ++a)
        #pragma unroll
        for (int b = 0; b < 4; ++b) acc[a][b] = 0;

    const int srow = tid >> 1, sc = (tid & 1) * 16;
    const u16* aB = A  + (size_t)(m0 + srow) * K + sc;
    const u16* bB = Bt + (size_t)(n0 + srow) * K + sc;

    for (int k0 = 0; k0 < K; k0 += 32) {
        __syncthreads();
        *(short8*)&As[srow][sc]     = *(const short8*)(aB + k0);
        *(short8*)&As[srow][sc + 8] = *(const short8*)(aB + k0 + 8);
        *(short8*)&Bs[srow][sc]     = *(const short8*)(bB + k0);
        *(short8*)&Bs[srow][sc + 8] = *(const short8*)(bB + k0 + 8);
        __syncthreads();
        short8 af[4], bf[4];
        #pragma unroll
        for (int i = 0; i < 4; ++i) af[i] = *(const short8*)&As[wm + i*16 + l15][lhi*8];
        #pragma unroll
        for (int i = 0; i < 4; ++i) bf[i] = *(const short8*)&Bs[wn + i*16 + l15][lhi*8];
        #pragma unroll
        for (int a = 0; a < 4; ++a)
            #pragma unroll
            for (int b = 0; b < 4; ++b)
                acc[a][b] = MFMA_16x16x32(af[a], bf[b], acc[a][b]);
    }
    #pragma unroll
    for (int a = 0; a < 4; ++a)
      #pragma unroll
      for (int b = 0; b < 4; ++b)
        #pragma unroll
        for (int r = 0; r < 4; ++r) {
            int m = m0 + wm + a*16 + lhi*4 + r;
            if (m < cnt) {
                int n = n0 + wn + b*16 + l15;
                int enc = list[e*CAP + m];
                float wgt = wts[e*CAP + m];
                int tok = enc >> 3, kk = enc & 7;
                Rbuf[((size_t)tok*NTOP + kk)*N + n] = f2b(acc[a][b][r] * wgt);
            }
        }
}

// ---------------- RoPE in-place on f32 qkv (fused buffer) -------------------
__global__ __launch_bounds__(256) void k_rope_f32(
    float* __restrict__ QKV,
    const float* __restrict__ Cs, const float* __restrict__ Sn)
{
    int id = blockIdx.x * 256 + threadIdx.x;   // TT * 20 * 64
    int pr = id & 63;
    int rest = id >> 6;
    int hh = rest % 20;
    int tok = rest / 20;
    if (tok >= TT) return;
    int d0 = pr * 2;
    float c0 = Cs[(size_t)tok*HDD + d0];
    float c1 = Cs[(size_t)tok*HDD + d0 + 1];
    float s0 = Sn[(size_t)tok*HDD + d0];
    float s1 = Sn[(size_t)tok*HDD + d0 + 1];
    float* p = QKV + (size_t)tok*3072 + (hh < HH ? hh*HDD : 2048 + (hh - HH)*HDD);
    float x0 = p[d0], x1 = p[d0+1];
    p[d0]     = x0*c0 - x1*s0;
    p[d0 + 1] = x1*c1 + x0*s1;
}

// ---------------- Split strided f32 into (hi,lo) bf16 -----------------------
__global__ __launch_bounds__(256) void k_split_s(
    const float* __restrict__ X, int stride, int cols,
    u16* __restrict__ Hi, u16* __restrict__ Lo)
{
    int id = blockIdx.x * 256 + threadIdx.x;
    int base = id * 8;
    int t = base / cols;
    int c = base - t * cols;
    const float* in = X + (size_t)t * stride + c;
    f32x4 v0 = *(const f32x4*)in;
    f32x4 v1 = *(const f32x4*)(in + 4);
    u16* h = Hi + (size_t)t * cols + c;
    u16* l = Lo + (size_t)t * cols + c;
    #pragma unroll
    for (int j = 0; j < 4; ++j) {
        fsplit(v0[j], h[j],   l[j]);
        fsplit(v1[j], h[4+j], l[4+j]);
    }
}

// ---------------- V from qkvf -> split V^T (b,hk,d,s) -----------------------
__global__ __launch_bounds__(256) void k_split_vt(
    const float* __restrict__ QKV, u16* __restrict__ Vth, u16* __restrict__ Vtl)
{
    int id = blockIdx.x * 256 + threadIdx.x;   // TT*HKK*HDD/8
    int oid = id * 8;
    int s0 = oid & (SS - 1);
    int r = oid >> 10;
    int d = r & (HDD - 1);
    int bh = r >> 7;
    int b = bh >> 2, hk = bh & 3;
    #pragma unroll
    for (int j = 0; j < 8; ++j) {
        int s = s0 + j;
        float v = QKV[(size_t)(b*SS + s)*3072 + 2560 + hk*HDD + d];
        fsplit(v, Vth[oid + j], Vtl[oid + j]);
    }
}

// ---------------- Flash attention, split-bf16 precision ---------------------
__global__ __launch_bounds__(256) void k_attn_hi(
    const u16* __restrict__ Qh, const u16* __restrict__ Ql,
    const u16* __restrict__ Kh, const u16* __restrict__ Kl,
    const u16* __restrict__ Vth, const u16* __restrict__ Vtl,
    u16* __restrict__ Oh, u16* __restrict__ Ol)
{
    const int tid = threadIdx.x;
    const int lane = tid & 63;
    const int w = tid >> 6;
    const int q0 = blockIdx.x * 64;
    const int b = blockIdx.y >> 4;
    const int h = blockIdx.y & 15;
    const int hk = h >> 2;
    const int l15 = lane & 15, lhi = lane >> 4;

    __shared__ u16 Ksh[32][136];
    __shared__ u16 Ksl[32][136];
    __shared__ u16 Vsh[128][40];
    __shared__ u16 Vsl[128][40];
    __shared__ u16 Psh[4][16][40];
    __shared__ u16 Psl[4][16][40];

    short8 qfh[4], qfl[4];
    {
        const int qrow = q0 + w*16 + l15;
        const u16* qph = Qh + ((size_t)(b*SS + qrow)*HH + h)*HDD;
        const u16* qpl = Ql + ((size_t)(b*SS + qrow)*HH + h)*HDD;
        #pragma unroll
        for (int c = 0; c < 4; ++c) {
            qfh[c] = *(const short8*)(qph + c*32 + lhi*8);
            qfl[c] = *(const short8*)(qpl + c*32 + lhi*8);
        }
    }

    f32x4 oacc[8];
    #pragma unroll
    for (int ch = 0; ch < 8; ++ch) oacc[ch] = 0;
    float m_r[4] = {-1e30f, -1e30f, -1e30f, -1e30f};
    float l_r[4] = {0.f, 0.f, 0.f, 0.f};

    const int nkt = (q0 + 64) >> 5;
    const int kr = tid >> 3, kc = (tid & 7) * 16;
    const int vd = tid >> 1, vj = (tid & 1) * 16;

    for (int kt = 0; kt < nkt; ++kt) {
        __syncthreads();
        {
            size_t koff = ((size_t)(b*SS + kt*32 + kr)*HKK + hk)*HDD + kc;
            *(short8*)&Ksh[kr][kc]     = *(const short8*)(Kh + koff);
            *(short8*)&Ksh[kr][kc + 8] = *(const short8*)(Kh + koff + 8);
            *(short8*)&Ksl[kr][kc]     = *(const short8*)(Kl + koff);
            *(short8*)&Ksl[kr][kc + 8] = *(const short8*)(Kl + koff + 8);
        }
        {
            size_t voff = ((size_t)(b*HKK + hk)*HDD + vd)*SS + kt*32 + vj;
            *(short8*)&Vsh[vd][vj]     = *(const short8*)(Vth + voff);
            *(short8*)&Vsh[vd][vj + 8] = *(const short8*)(Vth + voff + 8);
            *(short8*)&Vsl[vd][vj]     = *(const short8*)(Vtl + voff);
            *(short8*)&Vsl[vd][vj + 8] = *(const short8*)(Vtl + voff + 8);
        }
        __syncthreads();

        f32x4 s0 = 0, s1 = 0;
        #pragma unroll
        for (int c = 0; c < 4; ++c) {
            short8 kh0 = *(const short8*)&Ksh[l15][c*32 + lhi*8];
            short8 kl0 = *(const short8*)&Ksl[l15][c*32 + lhi*8];
            short8 kh1 = *(const short8*)&Ksh[16 + l15][c*32 + lhi*8];
            short8 kl1 = *(const short8*)&Ksl[16 + l15][c*32 + lhi*8];
            s0 = MFMA_16x16x32(qfh[c], kh0, s0);
            s0 = MFMA_16x16x32(qfh[c], kl0, s0);
            s0 = MFMA_16x16x32(qfl[c], kh0, s0);
            s1 = MFMA_16x16x32(qfh[c], kh1, s1);
            s1 = MFMA_16x16x32(qfh[c], kl1, s1);
            s1 = MFMA_16x16x32(qfl[c], kh1, s1);
        }
        const int irow0 = q0 + w*16 + lhi*4;
        const int j0 = kt*32 + l15;
        float ef[4];
        #pragma unroll
        for (int r = 0; r < 4; ++r) {
            float a0 = s0[r] * 0.08838834764831845f;
            float a1 = s1[r] * 0.08838834764831845f;
            const int ir = irow0 + r;
            if (j0 > ir) a0 = -1e30f;
            if (j0 + 16 > ir) a1 = -1e30f;
            float mx = fmaxf(a0, a1);
            #pragma unroll
            for (int o = 1; o < 16; o <<= 1) mx = fmaxf(mx, __shfl_xor(mx, o));
            float mn = fmaxf(m_r[r], mx);
            ef[r] = __expf(m_r[r] - mn);
            m_r[r] = mn;
            float p0 = __expf(a0 - mn);
            float p1 = __expf(a1 - mn);
            float ps = p0 + p1;
            #pragma unroll
            for (int o = 1; o < 16; o <<= 1) ps += __shfl_xor(ps, o);
            l_r[r] = l_r[r]*ef[r] + ps;
            fsplit(p0, Psh[w][lhi*4 + r][l15],      Psl[w][lhi*4 + r][l15]);
            fsplit(p1, Psh[w][lhi*4 + r][16 + l15], Psl[w][lhi*4 + r][16 + l15]);
        }
        #pragma unroll
        for (int ch = 0; ch < 8; ++ch) {
            f32x4 t = oacc[ch];
            t[0] *= ef[0]; t[1] *= ef[1]; t[2] *= ef[2]; t[3] *= ef[3];
            oacc[ch] = t;
        }
        __syncthreads();
        short8 pah = *(const short8*)&Psh[w][l15][lhi*8];
        short8 pal = *(const short8*)&Psl[w][l15][lhi*8];
        #pragma unroll
        for (int ch = 0; ch < 8; ++ch) {
            short8 bvh = *(const short8*)&Vsh[ch*16 + l15][lhi*8];
            short8 bvl = *(const short8*)&Vsl[ch*16 + l15][lhi*8];
            oacc[ch] = MFMA_16x16x32(pah, bvh, oacc[ch]);
            oacc[ch] = MFMA_16x16x32(pah, bvl, oacc[ch]);
            oacc[ch] = MFMA_16x16x32(pal, bvh, oacc[ch]);
        }
    }
    #pragma unroll
    for (int r = 0; r < 4; ++r) {
        const int row = q0 + w*16 + lhi*4 + r;
        const float inv = 1.0f / l_r[r];
        u16* oph = Oh + ((size_t)(b*SS + row)*HH + h)*HDD;
        u16* opl = Ol + ((size_t)(b*SS + row)*HH + h)*HDD;
        #pragma unroll
        for (int ch = 0; ch < 8; ++ch) {
            float o = oacc[ch][r] * inv;
            fsplit(o, oph[ch*16 + l15], opl[ch*16 + l15]);
        }
    }
}

// ---------------- Router: f32 logits, softmax, top-6, slot lists ------------
__global__ __launch_bounds__(256) void k_router(
    const float* __restrict__ X, const float* __restrict__ Wg,
    const float* __restrict__ bias,
    int* __restrict__ cnt, int* __restrict__ list, float* __restrict__ wts)
{
    const int t = blockIdx.x;
    const int e = threadIdx.x & 15, sl = threadIdx.x >> 4;
    const float* x = X + (size_t)t * DD;
    float part = 0.f;
    for (int i = 0; i < 128; ++i) {
        int k = sl * 128 + i;
        part += x[k] * Wg[(size_t)k * EE + e];
    }
    __shared__ float red[16][17];
    red[sl][e] = part;
    __syncthreads();
    if (threadIdx.x == 0) {
        float lg[16], pr[16];
        for (int ee = 0; ee < 16; ++ee) {
            float s = 0.f;
            for (int q = 0; q < 16; ++q) s += red[q][ee];
            lg[ee] = s;
        }
        float mx = lg[0];
        for (int ee = 1; ee < 16; ++ee) mx = fmaxf(mx, lg[ee]);
        float sum = 0.f;
        for (int ee = 0; ee < 16; ++ee) { pr[ee] = expf(lg[ee] - mx); sum += pr[ee]; }
        float isum = 1.0f / sum;
        for (int ee = 0; ee < 16; ++ee) pr[ee] *= isum;
        unsigned used = 0;
        int sel[NTOP]; float rw[NTOP]; float s6 = 0.f;
        for (int kk = 0; kk < NTOP; ++kk) {
            int best = 0; float bv = -1e30f;
            for (int ee = 0; ee < 16; ++ee) {
                if (used & (1u << ee)) continue;
                float sc = pr[ee] + bias[ee];
                if (sc > bv) { bv = sc; best = ee; }
            }
            used |= 1u << best;
            sel[kk] = best; rw[kk] = pr[best]; s6 += pr[best];
        }
        float inv6 = 1.0f / fmaxf(s6, 1e-12f);
        for (int kk = 0; kk < NTOP; ++kk) {
            int ee = sel[kk];
            int pos = atomicAdd(&cnt[ee], 1);
            list[ee*CAP + pos] = (t << 3) | kk;
            wts[ee*CAP + pos] = rw[kk] * inv6;
        }
    }
}

// ---------------- Final: out = h2 + shared + sum_kk routed ------------------
__global__ __launch_bounds__(256) void k_final(
    const float* __restrict__ h2, const float* __restrict__ yb,
    const u16* __restrict__ rb, float* __restrict__ out)
{
    int id = blockIdx.x * 256 + threadIdx.x;     // T*D/4
    size_t i4 = (size_t)id * 4;
    int t = id >> 9;
    int d = (id & 511) * 4;
    f32x4 acc = *(const f32x4*)(h2 + i4);
    f32x4 y = *(const f32x4*)(yb + i4);
    acc += y;
    #pragma unroll
    for (int kk = 0; kk < NTOP; ++kk) {
        s16x4 rv = *(const s16x4*)(rb + ((size_t)t*NTOP + kk)*DD + d);
        acc[0] += b2f((u16)rv[0]); acc[1] += b2f((u16)rv[1]);
        acc[2] += b2f((u16)rv[2]); acc[3] += b2f((u16)rv[3]);
    }
    *(f32x4*)(out + i4) = acc;
}

extern "C" void kernel_launch(void* const* d_in, const int* in_sizes, int n_in,
                              void* d_out, int out_size, void* d_ws, size_t ws_size,
                              hipStream_t stream)
{
    (void)in_sizes; (void)n_in; (void)out_size; (void)ws_size;
    const float* hidden = (const float*)d_in[0];
    const float* cosb   = (const float*)d_in[1];
    const float* sinb   = (const float*)d_in[2];
    const float* ln1    = (const float*)d_in[3];
    const float* ln2    = (const float*)d_in[4];
    const float* Wq     = (const float*)d_in[5];
    const float* Wk     = (const float*)d_in[6];
    const float* Wv     = (const float*)d_in[7];
    const float* Wo     = (const float*)d_in[8];
    const float* Wgate  = (const float*)d_in[9];
    const float* cbias  = (const float*)d_in[10];
    const float* Wg     = (const float*)d_in[11];
    const float* Wu     = (const float*)d_in[12];
    const float* Wd     = (const float*)d_in[13];
    const float* Wgs    = (const float*)d_in[14];
    const float* Wus    = (const float*)d_in[15];
    const float* Wds    = (const float*)d_in[16];
    float* out = (float*)d_out;

    char* ws = (char*)d_ws;
    size_t off = 0;
    auto alloc = [&](size_t bytes) {
        void* p = ws + off;
        off = (off + bytes + 255) & ~(size_t)255;
        return p;
    };
    // Pre-transposed bf16 weights
    u16* WqkvTh = (u16*)alloc((size_t)3072*2048*2);
    u16* WqkvTl = (u16*)alloc((size_t)3072*2048*2);
    u16* WoTh   = (u16*)alloc((size_t)2048*2048*2);
    u16* WoTl   = (u16*)alloc((size_t)2048*2048*2);
    u16* WgsT   = (u16*)alloc((size_t)2048*2048*2);
    u16* WusT   = (u16*)alloc((size_t)2048*2048*2);
    u16* WdsT   = (u16*)alloc((size_t)2048*2048*2);
    u16* WgT    = (u16*)alloc((size_t)EE*II*DD*2);
    u16* WuT    = (u16*)alloc((size_t)EE*II*DD*2);
    u16* WdT    = (u16*)alloc((size_t)EE*DD*II*2);
    // Activations
    u16*   x1h  = (u16*)  alloc((size_t)TT*DD*2);
    u16*   x1l  = (u16*)  alloc((size_t)TT*DD*2);
    float* qkvf = (float*)alloc((size_t)TT*3072*4);
    u16*   qh   = (u16*)  alloc((size_t)TT*HH*HDD*2);
    u16*   ql   = (u16*)  alloc((size_t)TT*HH*HDD*2);
    u16*   kh   = (u16*)  alloc((size_t)TT*HKK*HDD*2);
    u16*   kl   = (u16*)  alloc((size_t)TT*HKK*HDD*2);
    u16*   vth  = (u16*)  alloc((size_t)TT*HKK*HDD*2);
    u16*   vtl  = (u16*)  alloc((size_t)TT*HKK*HDD*2);
    u16*   aoh  = (u16*)  alloc((size_t)TT*HH*HDD*2);
    u16*   aol  = (u16*)  alloc((size_t)TT*HH*HDD*2);
    float* h2   = (float*)alloc((size_t)TT*DD*4);
    u16*   x2   = (u16*)  alloc((size_t)TT*DD*2);
    float* x2f  = (float*)alloc((size_t)TT*DD*4);
    int*   cnt  = (int*)  alloc(256);
    int*   lst  = (int*)  alloc((size_t)EE*CAP*4);
    float* wts  = (float*)alloc((size_t)EE*CAP*4);
    u16*   hE   = (u16*)  alloc((size_t)EE*CAP*II*2);
    u16*   rbuf = (u16*)  alloc((size_t)TT*NTOP*DD*2);
    // Aliases (lifetimes disjoint):
    u16*   hs   = x1h;            // [TT][ISS] bf16 = 8MB, x1h dead after QKV
    float* ybuf = qkvf;           // [TT][DD] f32 = 16MB, qkvf dead after splits

    // ---- Weight prep (transpose + bf16 convert [+ split]) ----
    k_prep<true ><<<dim3(64,64,1), 256, 0, stream>>>(Wq, WqkvTh, WqkvTl, 2048, 2048);
    k_prep<true ><<<dim3(16,64,1), 256, 0, stream>>>(Wk, WqkvTh + (size_t)2048*2048, WqkvTl + (size_t)2048*2048, 2048, 512);
    k_prep<true ><<<dim3(16,64,1), 256, 0, stream>>>(Wv, WqkvTh + (size_t)2560*2048, WqkvTl + (size_t)2560*2048, 2048, 512);
    k_prep<true ><<<dim3(64,64,1), 256, 0, stream>>>(Wo, WoTh, WoTl, 2048, 2048);
    k_prep<false><<<dim3(64,64,1), 256, 0, stream>>>(Wgs, WgsT, nullptr, 2048, 2048);
    k_prep<false><<<dim3(64,64,1), 256, 0, stream>>>(Wus, WusT, nullptr, 2048, 2048);
    k_prep<false><<<dim3(64,64,1), 256, 0, stream>>>(Wds, WdsT, nullptr, 2048, 2048);
    k_prep<false><<<dim3(32,64,EE), 256, 0, stream>>>(Wg, WgT, nullptr, 2048, 1024);
    k_prep<false><<<dim3(32,64,EE), 256, 0, stream>>>(Wu, WuT, nullptr, 2048, 1024);
    k_prep<false><<<dim3(64,32,EE), 256, 0, stream>>>(Wd, WdT, nullptr, 1024, 2048);

    // ---- Attention path (split-bf16 high precision) ----
    k_rmsnorm_split<<<TT, 256, 0, stream>>>(hidden, ln1, x1h, x1l);
    k_gemm_hi<2><<<dim3(24,16), 256, 0, stream>>>(x1h, x1l, WqkvTh, WqkvTl, qkvf, nullptr, TT, 3072, DD);
    k_rope_f32<<<(TT*20*64)/256, 256, 0, stream>>>(qkvf, cosb, sinb);
    k_split_s<<<(TT*2048/8)/256, 256, 0, stream>>>(qkvf, 3072, 2048, qh, ql);
    k_split_s<<<(TT*512/8)/256, 256, 0, stream>>>(qkvf + 2048, 3072, 512, kh, kl);
    k_split_vt<<<(TT*HKK*HDD/8)/256, 256, 0, stream>>>(qkvf, vth, vtl);
    k_attn_hi<<<dim3(SS/64, BB*HH), 256, 0, stream>>>(qh, ql, kh, kl, vth, vtl, aoh, aol);
    k_gemm_hi<1><<<dim3(16,16), 256, 0, stream>>>(aoh, aol, WoTh, WoTl, h2, hidden, TT, DD, HH*HDD);

    // ---- MoE path ----
    k_rmsnorm_bf<<<TT, 256, 0, stream>>>(h2, ln2, x2, x2f);
    hipMemsetAsync(cnt, 0, 256, stream);
    k_router<<<TT, 256, 0, stream>>>(x2f, Wgate, cbias, cnt, lst, wts);
    k_glu<false><<<dim3(ISS/64, TT/128, 1), 256, 0, stream>>>(x2, WgsT, WusT, hs, nullptr, nullptr, TT, ISS, DD);
    k_gemm<2><<<dim3(16,16), 256, 0, stream>>>(hs, WdsT, ybuf, TT, DD, ISS);
    k_glu<true><<<dim3(II/64, CAP/128, EE), 256, 0, stream>>>(x2, WgT, WuT, hE, lst, cnt, CAP, II, DD);
    k_down_scatter<<<dim3(DD/128, CAP/128, EE), 256, 0, stream>>>(hE, WdT, rbuf, lst, wts, cnt, DD, II);
    k_final<<<(TT*DD/4)/256, 256, 0, stream>>>(h2, ybuf, rbuf, out);
}

// Round 5
// 1122.549 us; speedup vs baseline: 1.7808x; 1.0175x over previous
//
#include <hip/hip_runtime.h>
#include <cstdint>

typedef unsigned short u16;
typedef __attribute__((ext_vector_type(8))) short short8;
typedef __attribute__((ext_vector_type(4))) short s16x4;
typedef __attribute__((ext_vector_type(4))) float f32x4;

#define MFMA_16x16x32(a,b,c) __builtin_amdgcn_mfma_f32_16x16x32_bf16(a,b,c,0,0,0)

// async global->LDS, 16B per lane, wave covers 1024B (16 rows of a [*][32] bf16 tile)
#define GLDS16(lds, g) __builtin_amdgcn_global_load_lds( \
    (const __attribute__((address_space(1))) unsigned int*)(g), \
    (__attribute__((address_space(3))) unsigned int*)(lds), 16, 0, 0)

#define BB 2
#define SS 1024
#define DD 2048
#define HH 16
#define HKK 4
#define HDD 128
#define EE 16
#define NTOP 6
#define II 1024
#define ISS 2048
#define TT 2048
#define CAP 2048

__device__ __forceinline__ u16 f2b(float f) {
    union { float f; uint32_t u; } v; v.f = f;
    uint32_t r = v.u + 0x7FFFu + ((v.u >> 16) & 1u);
    return (u16)(r >> 16);
}
__device__ __forceinline__ float b2f(u16 h) {
    union { uint32_t u; float f; } v; v.u = ((uint32_t)h) << 16;
    return v.f;
}
__device__ __forceinline__ void fsplit(float f, u16& hi, u16& lo) {
    u16 h = f2b(f);
    hi = h;
    lo = f2b(f - b2f(h));
}

// ---------- Prep: transpose+convert W f32 [R][C] -> bf16 [C][R] (hi[,lo]) ---
template<bool SPLIT>
__global__ __launch_bounds__(256) void k_prep(
    const float* __restrict__ In, u16* __restrict__ Oh, u16* __restrict__ Ol,
    int R, int C)
{
    const size_t zoff = (size_t)blockIdx.z * R * C;
    In += zoff; Oh += zoff; if (SPLIT) Ol += zoff;
    const int r0 = blockIdx.y * 32, c0 = blockIdx.x * 32;
    __shared__ float tile[32][33];
    const int tx = threadIdx.x & 31, ty = threadIdx.x >> 5;
    #pragma unroll
    for (int i = 0; i < 4; ++i)
        tile[ty + i*8][tx] = In[(size_t)(r0 + ty + i*8)*C + c0 + tx];
    __syncthreads();
    const int c = threadIdx.x >> 3, rs = (threadIdx.x & 7) * 4;
    s16x4 hv, lv;
    #pragma unroll
    for (int j = 0; j < 4; ++j) {
        float f = tile[rs + j][c];
        u16 hb = f2b(f);
        hv[j] = (short)hb;
        if (SPLIT) lv[j] = (short)f2b(f - b2f(hb));
        else lv[j] = 0;
    }
    *(s16x4*)(Oh + (size_t)(c0 + c)*R + r0 + rs) = hv;
    if (SPLIT) *(s16x4*)(Ol + (size_t)(c0 + c)*R + r0 + rs) = lv;
}

// ---------------- RMSNorm f32 in -> split bf16 (hi,lo) ----------------------
__global__ __launch_bounds__(256) void k_rmsnorm_split(
    const float* __restrict__ X, const float* __restrict__ Wt,
    u16* __restrict__ Oh, u16* __restrict__ Ol)
{
    const int t = blockIdx.x;
    const float* x = X + (size_t)t * DD;
    const int base = threadIdx.x * 8;
    f32x4 v0 = *(const f32x4*)(x + base);
    f32x4 v1 = *(const f32x4*)(x + base + 4);
    float ss = 0.f;
    #pragma unroll
    for (int j = 0; j < 4; ++j) ss += v0[j]*v0[j] + v1[j]*v1[j];
    #pragma unroll
    for (int o = 1; o < 64; o <<= 1) ss += __shfl_xor(ss, o);
    __shared__ float red[4];
    if ((threadIdx.x & 63) == 0) red[threadIdx.x >> 6] = ss;
    __syncthreads();
    float tot = red[0] + red[1] + red[2] + red[3];
    float inv = rsqrtf(tot * (1.0f/DD) + 1e-6f);
    f32x4 w0 = *(const f32x4*)(Wt + base);
    f32x4 w1 = *(const f32x4*)(Wt + base + 4);
    u16* oh = Oh + (size_t)t*DD + base;
    u16* ol = Ol + (size_t)t*DD + base;
    #pragma unroll
    for (int j = 0; j < 4; ++j) {
        float y0 = v0[j]*inv*w0[j];
        float y1 = v1[j]*inv*w1[j];
        fsplit(y0, oh[j],   ol[j]);
        fsplit(y1, oh[4+j], ol[4+j]);
    }
}

// ---------------- RMSNorm f32 in -> bf16 + f32 ------------------------------
__global__ __launch_bounds__(256) void k_rmsnorm_bf(
    const float* __restrict__ X, const float* __restrict__ Wt,
    u16* __restrict__ Ob, float* __restrict__ Of)
{
    const int t = blockIdx.x;
    const float* x = X + (size_t)t * DD;
    const int base = threadIdx.x * 8;
    f32x4 v0 = *(const f32x4*)(x + base);
    f32x4 v1 = *(const f32x4*)(x + base + 4);
    float ss = 0.f;
    #pragma unroll
    for (int j = 0; j < 4; ++j) ss += v0[j]*v0[j] + v1[j]*v1[j];
    #pragma unroll
    for (int o = 1; o < 64; o <<= 1) ss += __shfl_xor(ss, o);
    __shared__ float red[4];
    if ((threadIdx.x & 63) == 0) red[threadIdx.x >> 6] = ss;
    __syncthreads();
    float tot = red[0] + red[1] + red[2] + red[3];
    float inv = rsqrtf(tot * (1.0f/DD) + 1e-6f);
    f32x4 w0 = *(const f32x4*)(Wt + base);
    f32x4 w1 = *(const f32x4*)(Wt + base + 4);
    u16* ob = Ob + (size_t)t*DD + base;
    float* of = Of + (size_t)t*DD + base;
    #pragma unroll
    for (int j = 0; j < 4; ++j) {
        float y0 = v0[j]*inv*w0[j];
        float y1 = v1[j]*inv*w1[j];
        ob[j] = f2b(y0); ob[4+j] = f2b(y1);
        of[j] = y0;      of[4+j] = y1;
    }
}

// ------- High-precision GEMM: C = (Ah+Al) @ (Bh+Bl)^T, pre-split bf16 -------
// EPI 1: f32 store + residual; 2: f32 store
template<int EPI>
__global__ __launch_bounds__(256) void k_gemm_hi(
    const u16* __restrict__ Ah, const u16* __restrict__ Al,
    const u16* __restrict__ Bth, const u16* __restrict__ Btl,
    float* __restrict__ C, const float* __restrict__ Res,
    int M, int N, int K)
{
    __shared__ u16 Ash[128][32];
    __shared__ u16 Asl[128][32];
    __shared__ u16 Bsh[128][32];
    __shared__ u16 Bsl[128][32];
    const int tid = threadIdx.x;
    const int lane = tid & 63;
    const int w = tid >> 6;
    const int m0 = blockIdx.y * 128, n0 = blockIdx.x * 128;
    const int wm = (w >> 1) * 64, wn = (w & 1) * 64;
    const int l15 = lane & 15, lhi = lane >> 4;
    f32x4 acc[4][4];
    #pragma unroll
    for (int a = 0; a < 4; ++a)
        #pragma unroll
        for (int b = 0; b < 4; ++b) acc[a][b] = 0;

    // async-stage lane mapping: lane covers row (lane>>2), col bytes (lane&3)*16
    const int gr = w*32 + (lane >> 2);
    const int gc = (lane & 3) * 8;
    const u16* ahP0 = Ah  + (size_t)(m0 + gr) * K + gc;
    const u16* alP0 = Al  + (size_t)(m0 + gr) * K + gc;
    const u16* bhP0 = Bth + (size_t)(n0 + gr) * K + gc;
    const u16* blP0 = Btl + (size_t)(n0 + gr) * K + gc;
    const size_t r16 = (size_t)16 * K;

    for (int k0 = 0; k0 < K; k0 += 32) {
        __syncthreads();
        GLDS16(&Ash[w*32][0],      ahP0 + k0);
        GLDS16(&Ash[w*32 + 16][0], ahP0 + r16 + k0);
        GLDS16(&Asl[w*32][0],      alP0 + k0);
        GLDS16(&Asl[w*32 + 16][0], alP0 + r16 + k0);
        GLDS16(&Bsh[w*32][0],      bhP0 + k0);
        GLDS16(&Bsh[w*32 + 16][0], bhP0 + r16 + k0);
        GLDS16(&Bsl[w*32][0],      blP0 + k0);
        GLDS16(&Bsl[w*32 + 16][0], blP0 + r16 + k0);
        __syncthreads();
        short8 afh[4], afl[4], bfh[4], bfl[4];
        #pragma unroll
        for (int i = 0; i < 4; ++i) {
            afh[i] = *(const short8*)&Ash[wm + i*16 + l15][lhi*8];
            afl[i] = *(const short8*)&Asl[wm + i*16 + l15][lhi*8];
            bfh[i] = *(const short8*)&Bsh[wn + i*16 + l15][lhi*8];
            bfl[i] = *(const short8*)&Bsl[wn + i*16 + l15][lhi*8];
        }
        #pragma unroll
        for (int a = 0; a < 4; ++a)
            #pragma unroll
            for (int b = 0; b < 4; ++b) {
                acc[a][b] = MFMA_16x16x32(afh[a], bfh[b], acc[a][b]);
                acc[a][b] = MFMA_16x16x32(afh[a], bfl[b], acc[a][b]);
                acc[a][b] = MFMA_16x16x32(afl[a], bfh[b], acc[a][b]);
            }
    }
    #pragma unroll
    for (int a = 0; a < 4; ++a)
      #pragma unroll
      for (int b = 0; b < 4; ++b)
        #pragma unroll
        for (int r = 0; r < 4; ++r) {
            int m = m0 + wm + a*16 + lhi*4 + r;
            int n = n0 + wn + b*16 + l15;
            size_t off = (size_t)m * N + n;
            float v = acc[a][b][r];
            if (EPI == 1) C[off] = v + Res[off];
            else C[off] = v;
        }
}

// ---------------- Dense GEMM: C(MxN) = A_bf16 @ Bt_bf16^T -------------------
// EPI 0: bf16 store; 2: f32 store
template<int EPI>
__global__ __launch_bounds__(256) void k_gemm(
    const u16* __restrict__ A, const u16* __restrict__ Bt,
    void* __restrict__ C, int M, int N, int K)
{
    __shared__ u16 As[128][32];
    __shared__ u16 Bs[128][32];
    const int tid = threadIdx.x;
    const int lane = tid & 63;
    const int w = tid >> 6;
    const int m0 = blockIdx.y * 128, n0 = blockIdx.x * 128;
    const int wm = (w >> 1) * 64, wn = (w & 1) * 64;
    const int l15 = lane & 15, lhi = lane >> 4;
    f32x4 acc[4][4];
    #pragma unroll
    for (int a = 0; a < 4; ++a)
        #pragma unroll
        for (int b = 0; b < 4; ++b) acc[a][b] = 0;

    const int gr = w*32 + (lane >> 2);
    const int gc = (lane & 3) * 8;
    const u16* aP0 = A  + (size_t)(m0 + gr) * K + gc;
    const u16* bP0 = Bt + (size_t)(n0 + gr) * K + gc;
    const size_t r16 = (size_t)16 * K;

    for (int k0 = 0; k0 < K; k0 += 32) {
        __syncthreads();
        GLDS16(&As[w*32][0],      aP0 + k0);
        GLDS16(&As[w*32 + 16][0], aP0 + r16 + k0);
        GLDS16(&Bs[w*32][0],      bP0 + k0);
        GLDS16(&Bs[w*32 + 16][0], bP0 + r16 + k0);
        __syncthreads();
        short8 af[4], bf[4];
        #pragma unroll
        for (int i = 0; i < 4; ++i) af[i] = *(const short8*)&As[wm + i*16 + l15][lhi*8];
        #pragma unroll
        for (int i = 0; i < 4; ++i) bf[i] = *(const short8*)&Bs[wn + i*16 + l15][lhi*8];
        #pragma unroll
        for (int a = 0; a < 4; ++a)
            #pragma unroll
            for (int b = 0; b < 4; ++b)
                acc[a][b] = MFMA_16x16x32(af[a], bf[b], acc[a][b]);
    }
    #pragma unroll
    for (int a = 0; a < 4; ++a)
      #pragma unroll
      for (int b = 0; b < 4; ++b)
        #pragma unroll
        for (int r = 0; r < 4; ++r) {
            int m = m0 + wm + a*16 + lhi*4 + r;
            int n = n0 + wn + b*16 + l15;
            size_t off = (size_t)m * N + n;
            float v = acc[a][b][r];
            if (EPI == 0) ((u16*)C)[off] = f2b(v);
            else ((float*)C)[off] = v;
        }
}

// ---------------- Fused GLU GEMM: h = silu(A@W1) * (A@W2), bf16 out ---------
template<bool GATHER>
__global__ __launch_bounds__(256) void k_glu(
    const u16* __restrict__ Xb, const u16* __restrict__ W1t,
    const u16* __restrict__ W2t, u16* __restrict__ Hout,
    const int* __restrict__ list, const int* __restrict__ cntp,
    int M, int NE, int K)
{
    const int e = GATHER ? blockIdx.z : 0;
    const int cnt = GATHER ? cntp[e] : M;
    const int m0 = blockIdx.y * 128;
    if (m0 >= cnt) return;
    const int n0 = blockIdx.x * 64;
    const u16* w1 = W1t + (size_t)e * NE * K;
    const u16* w2 = W2t + (size_t)e * NE * K;
    u16* hout = Hout + (size_t)e * CAP * NE;
    const int* lst = GATHER ? (list + e * CAP) : nullptr;

    __shared__ u16 As[128][32];
    __shared__ u16 B1s[64][32];
    __shared__ u16 B2s[64][32];

    const int tid = threadIdx.x, lane = tid & 63, w = tid >> 6;
    const int wm = (w >> 1) * 64, wn = (w & 1) * 32;
    const int l15 = lane & 15, lhi = lane >> 4;
    f32x4 acc1[4][2], acc2[4][2];
    #pragma unroll
    for (int a = 0; a < 4; ++a)
        #pragma unroll
        for (int j = 0; j < 2; ++j) { acc1[a][j] = 0; acc2[a][j] = 0; }

    const int gr  = w*32 + (lane >> 2);
    const int grB = w*16 + (lane >> 2);
    const int gc  = (lane & 3) * 8;
    int arow0, arow1;
    if (GATHER) {
        int mr0 = m0 + gr, mr1 = m0 + gr + 16;
        arow0 = (mr0 < cnt) ? (lst[mr0] >> 3) : 0;
        arow1 = (mr1 < cnt) ? (lst[mr1] >> 3) : 0;
    } else { arow0 = m0 + gr; arow1 = m0 + gr + 16; }
    const u16* aP0 = Xb + (size_t)arow0 * K + gc;
    const u16* aP1 = Xb + (size_t)arow1 * K + gc;
    const u16* b1P = w1 + (size_t)(n0 + grB) * K + gc;
    const u16* b2P = w2 + (size_t)(n0 + grB) * K + gc;

    for (int k0 = 0; k0 < K; k0 += 32) {
        __syncthreads();
        GLDS16(&As[w*32][0],      aP0 + k0);
        GLDS16(&As[w*32 + 16][0], aP1 + k0);
        GLDS16(&B1s[w*16][0],     b1P + k0);
        GLDS16(&B2s[w*16][0],     b2P + k0);
        __syncthreads();
        short8 af[4], b1[2], b2[2];
        #pragma unroll
        for (int i = 0; i < 4; ++i) af[i] = *(const short8*)&As[wm + i*16 + l15][lhi*8];
        #pragma unroll
        for (int j = 0; j < 2; ++j) {
            b1[j] = *(const short8*)&B1s[wn + j*16 + l15][lhi*8];
            b2[j] = *(const short8*)&B2s[wn + j*16 + l15][lhi*8];
        }
        #pragma unroll
        for (int a = 0; a < 4; ++a)
            #pragma unroll
            for (int j = 0; j < 2; ++j) {
                acc1[a][j] = MFMA_16x16x32(af[a], b1[j], acc1[a][j]);
                acc2[a][j] = MFMA_16x16x32(af[a], b2[j], acc2[a][j]);
            }
    }
    #pragma unroll
    for (int a = 0; a < 4; ++a)
      #pragma unroll
      for (int j = 0; j < 2; ++j)
        #pragma unroll
        for (int r = 0; r < 4; ++r) {
            int m = m0 + wm + a*16 + lhi*4 + r;
            if (m < cnt) {
                int n = n0 + wn + j*16 + l15;
                float g = acc1[a][j][r], u = acc2[a][j][r];
                float hval = g / (1.0f + __expf(-g)) * u;
                hout[(size_t)m * NE + n] = f2b(hval);
            }
        }
}

// ---------------- Routed down GEMM with scatter + weight --------------------
__global__ __launch_bounds__(256) void k_down_scatter(
    const u16* __restrict__ Hb, const u16* __restrict__ WdTt,
    u16* __restrict__ Rbuf, const int* __restrict__ list,
    const float* __restrict__ wts, const int* __restrict__ cntp,
    int N, int K)
{
    const int e = blockIdx.z;
    const int cnt = cntp[e];
    const int m0 = blockIdx.y * 128;
    if (m0 >= cnt) return;
    const int n0 = blockIdx.x * 128;
    const u16* A  = Hb   + (size_t)e * CAP * K;
    const u16* Bt = WdTt + (size_t)e * N * K;

    __shared__ u16 As[128][32];
    __shared__ u16 Bs[128][32];
    const int tid = threadIdx.x, lane = tid & 63, w = tid >> 6;
    const int wm = (w >> 1) * 64, wn = (w & 1) * 64;
    const int l15 = lane & 15, lhi = lane >> 4;
    f32x4 acc[4][4];
    #pragma unroll
    for (int a = 0; a < 4; ++a)
        #pragma unroll
        for (int b = 0; b < 4; ++b) acc[a][b] = 0;

    const int gr = w*32 + (lane >> 2);
    const int gc = (lane & 3) * 8;
    const u16* aP0 = A  + (size_t)(m0 + gr) * K + gc;
    const u16* bP0 = Bt + (size_t)(n0 + gr) * K + gc;
    const size_t r16 = (size_t)16 * K;

    for (int k0 = 0; k0 < K; k0 += 32) {
        __syncthreads();
        GLDS16(&As[w*32][0],      aP0 + k0);
        GLDS16(&As[w*32 + 16][0], aP0 + r16 + k0);
        GLDS16(&Bs[w*32][0],      bP0 + k0);
        GLDS16(&Bs[w*32 + 16][0], bP0 + r16 + k0);
        __syncthreads();
        short8 af[4], bf[4];
        #pragma unroll
        for (int i = 0; i < 4; ++i) af[i] = *(const short8*)&As[wm + i*16 + l15][lhi*8];
        #pragma unroll
        for (int i = 0; i < 4; ++i) bf[i] = *(const short8*)&Bs[wn + i*16 + l15][lhi*8];
        #pragma unroll
        for (int a = 0; a < 4; ++a)
            #pragma unroll
            for (int b = 0; b < 4; ++b)
                acc[a][b] = MFMA_16x16x32(af[a], bf[b], acc[a][b]);
    }
    #pragma unroll
    for (int a = 0; a < 4; ++a)
      #pragma unroll
      for (int b = 0; b < 4; ++b)
        #pragma unroll
        for (int r = 0; r < 4; ++r) {
            int m = m0 + wm + a*16 + lhi*4 + r;
            if (m < cnt) {
                int n = n0 + wn + b*16 + l15;
                int enc = list[e*CAP + m];
                float wgt = wts[e*CAP + m];
                int tok = enc >> 3, kk = enc & 7;
                Rbuf[((size_t)tok*NTOP + kk)*N + n] = f2b(acc[a][b][r] * wgt);
            }
        }
}

// ---------------- RoPE in-place on f32 qkv (fused buffer) -------------------
__global__ __launch_bounds__(256) void k_rope_f32(
    float* __restrict__ QKV,
    const float* __restrict__ Cs, const float* __restrict__ Sn)
{
    int id = blockIdx.x * 256 + threadIdx.x;   // TT * 20 * 64
    int pr = id & 63;
    int rest = id >> 6;
    int hh = rest % 20;
    int tok = rest / 20;
    if (tok >= TT) return;
    int d0 = pr * 2;
    float c0 = Cs[(size_t)tok*HDD + d0];
    float c1 = Cs[(size_t)tok*HDD + d0 + 1];
    float s0 = Sn[(size_t)tok*HDD + d0];
    float s1 = Sn[(size_t)tok*HDD + d0 + 1];
    float* p = QKV + (size_t)tok*3072 + (hh < HH ? hh*HDD : 2048 + (hh - HH)*HDD);
    float x0 = p[d0], x1 = p[d0+1];
    p[d0]     = x0*c0 - x1*s0;
    p[d0 + 1] = x1*c1 + x0*s1;
}

// ---------------- Split strided f32 into (hi,lo) bf16 -----------------------
__global__ __launch_bounds__(256) void k_split_s(
    const float* __restrict__ X, int stride, int cols,
    u16* __restrict__ Hi, u16* __restrict__ Lo)
{
    int id = blockIdx.x * 256 + threadIdx.x;
    int base = id * 8;
    int t = base / cols;
    int c = base - t * cols;
    const float* in = X + (size_t)t * stride + c;
    f32x4 v0 = *(const f32x4*)in;
    f32x4 v1 = *(const f32x4*)(in + 4);
    u16* h = Hi + (size_t)t * cols + c;
    u16* l = Lo + (size_t)t * cols + c;
    #pragma unroll
    for (int j = 0; j < 4; ++j) {
        fsplit(v0[j], h[j],   l[j]);
        fsplit(v1[j], h[4+j], l[4+j]);
    }
}

// ---------------- V from qkvf -> split V^T (b,hk,d,s) -----------------------
__global__ __launch_bounds__(256) void k_split_vt(
    const float* __restrict__ QKV, u16* __restrict__ Vth, u16* __restrict__ Vtl)
{
    int id = blockIdx.x * 256 + threadIdx.x;   // TT*HKK*HDD/8
    int oid = id * 8;
    int s0 = oid & (SS - 1);
    int r = oid >> 10;
    int d = r & (HDD - 1);
    int bh = r >> 7;
    int b = bh >> 2, hk = bh & 3;
    #pragma unroll
    for (int j = 0; j < 8; ++j) {
        int s = s0 + j;
        float v = QKV[(size_t)(b*SS + s)*3072 + 2560 + hk*HDD + d];
        fsplit(v, Vth[oid + j], Vtl[oid + j]);
    }
}

// ---------------- Flash attention, split-bf16 precision ---------------------
__global__ __launch_bounds__(256) void k_attn_hi(
    const u16* __restrict__ Qh, const u16* __restrict__ Ql,
    const u16* __restrict__ Kh, const u16* __restrict__ Kl,
    const u16* __restrict__ Vth, const u16* __restrict__ Vtl,
    u16* __restrict__ Oh, u16* __restrict__ Ol)
{
    const int tid = threadIdx.x;
    const int lane = tid & 63;
    const int w = tid >> 6;
    const int q0 = blockIdx.x * 64;
    const int b = blockIdx.y >> 4;
    const int h = blockIdx.y & 15;
    const int hk = h >> 2;
    const int l15 = lane & 15, lhi = lane >> 4;

    __shared__ u16 Ksh[32][136];
    __shared__ u16 Ksl[32][136];
    __shared__ u16 Vsh[128][40];
    __shared__ u16 Vsl[128][40];
    __shared__ u16 Psh[4][16][40];
    __shared__ u16 Psl[4][16][40];

    short8 qfh[4], qfl[4];
    {
        const int qrow = q0 + w*16 + l15;
        const u16* qph = Qh + ((size_t)(b*SS + qrow)*HH + h)*HDD;
        const u16* qpl = Ql + ((size_t)(b*SS + qrow)*HH + h)*HDD;
        #pragma unroll
        for (int c = 0; c < 4; ++c) {
            qfh[c] = *(const short8*)(qph + c*32 + lhi*8);
            qfl[c] = *(const short8*)(qpl + c*32 + lhi*8);
        }
    }

    f32x4 oacc[8];
    #pragma unroll
    for (int ch = 0; ch < 8; ++ch) oacc[ch] = 0;
    float m_r[4] = {-1e30f, -1e30f, -1e30f, -1e30f};
    float l_r[4] = {0.f, 0.f, 0.f, 0.f};

    const int nkt = (q0 + 64) >> 5;
    const int kr = tid >> 3, kc = (tid & 7) * 16;
    const int vd = tid >> 1, vj = (tid & 1) * 16;

    for (int kt = 0; kt < nkt; ++kt) {
        __syncthreads();
        {
            size_t koff = ((size_t)(b*SS + kt*32 + kr)*HKK + hk)*HDD + kc;
            *(short8*)&Ksh[kr][kc]     = *(const short8*)(Kh + koff);
            *(short8*)&Ksh[kr][kc + 8] = *(const short8*)(Kh + koff + 8);
            *(short8*)&Ksl[kr][kc]     = *(const short8*)(Kl + koff);
            *(short8*)&Ksl[kr][kc + 8] = *(const short8*)(Kl + koff + 8);
        }
        {
            size_t voff = ((size_t)(b*HKK + hk)*HDD + vd)*SS + kt*32 + vj;
            *(short8*)&Vsh[vd][vj]     = *(const short8*)(Vth + voff);
            *(short8*)&Vsh[vd][vj + 8] = *(const short8*)(Vth + voff + 8);
            *(short8*)&Vsl[vd][vj]     = *(const short8*)(Vtl + voff);
            *(short8*)&Vsl[vd][vj + 8] = *(const short8*)(Vtl + voff + 8);
        }
        __syncthreads();

        f32x4 s0 = 0, s1 = 0;
        #pragma unroll
        for (int c = 0; c < 4; ++c) {
            short8 kh0 = *(const short8*)&Ksh[l15][c*32 + lhi*8];
            short8 kl0 = *(const short8*)&Ksl[l15][c*32 + lhi*8];
            short8 kh1 = *(const short8*)&Ksh[16 + l15][c*32 + lhi*8];
            short8 kl1 = *(const short8*)&Ksl[16 + l15][c*32 + lhi*8];
            s0 = MFMA_16x16x32(qfh[c], kh0, s0);
            s0 = MFMA_16x16x32(qfh[c], kl0, s0);
            s0 = MFMA_16x16x32(qfl[c], kh0, s0);
            s1 = MFMA_16x16x32(qfh[c], kh1, s1);
            s1 = MFMA_16x16x32(qfh[c], kl1, s1);
            s1 = MFMA_16x16x32(qfl[c], kh1, s1);
        }
        const int irow0 = q0 + w*16 + lhi*4;
        const int j0 = kt*32 + l15;
        float ef[4];
        #pragma unroll
        for (int r = 0; r < 4; ++r) {
            float a0 = s0[r] * 0.08838834764831845f;
            float a1 = s1[r] * 0.08838834764831845f;
            const int ir = irow0 + r;
            if (j0 > ir) a0 = -1e30f;
            if (j0 + 16 > ir) a1 = -1e30f;
            float mx = fmaxf(a0, a1);
            #pragma unroll
            for (int o = 1; o < 16; o <<= 1) mx = fmaxf(mx, __shfl_xor(mx, o));
            float mn = fmaxf(m_r[r], mx);
            ef[r] = __expf(m_r[r] - mn);
            m_r[r] = mn;
            float p0 = __expf(a0 - mn);
            float p1 = __expf(a1 - mn);
            float ps = p0 + p1;
            #pragma unroll
            for (int o = 1; o < 16; o <<= 1) ps += __shfl_xor(ps, o);
            l_r[r] = l_r[r]*ef[r] + ps;
            fsplit(p0, Psh[w][lhi*4 + r][l15],      Psl[w][lhi*4 + r][l15]);
            fsplit(p1, Psh[w][lhi*4 + r][16 + l15], Psl[w][lhi*4 + r][16 + l15]);
        }
        #pragma unroll
        for (int ch = 0; ch < 8; ++ch) {
            f32x4 t = oacc[ch];
            t[0] *= ef[0]; t[1] *= ef[1]; t[2] *= ef[2]; t[3] *= ef[3];
            oacc[ch] = t;
        }
        __syncthreads();
        short8 pah = *(const short8*)&Psh[w][l15][lhi*8];
        short8 pal = *(const short8*)&Psl[w][l15][lhi*8];
        #pragma unroll
        for (int ch = 0; ch < 8; ++ch) {
            short8 bvh = *(const short8*)&Vsh[ch*16 + l15][lhi*8];
            short8 bvl = *(const short8*)&Vsl[ch*16 + l15][lhi*8];
            oacc[ch] = MFMA_16x16x32(pah, bvh, oacc[ch]);
            oacc[ch] = MFMA_16x16x32(pah, bvl, oacc[ch]);
            oacc[ch] = MFMA_16x16x32(pal, bvh, oacc[ch]);
        }
    }
    #pragma unroll
    for (int r = 0; r < 4; ++r) {
        const int row = q0 + w*16 + lhi*4 + r;
        const float inv = 1.0f / l_r[r];
        u16* oph = Oh + ((size_t)(b*SS + row)*HH + h)*HDD;
        u16* opl = Ol + ((size_t)(b*SS + row)*HH + h)*HDD;
        #pragma unroll
        for (int ch = 0; ch < 8; ++ch) {
            float o = oacc[ch][r] * inv;
            fsplit(o, oph[ch*16 + l15], opl[ch*16 + l15]);
        }
    }
}

// ---------------- Router: f32 logits, softmax, top-6, slot lists ------------
__global__ __launch_bounds__(256) void k_router(
    const float* __restrict__ X, const float* __restrict__ Wg,
    const float* __restrict__ bias,
    int* __restrict__ cnt, int* __restrict__ list, float* __restrict__ wts)
{
    const int t = blockIdx.x;
    const int e = threadIdx.x & 15, sl = threadIdx.x >> 4;
    const float* x = X + (size_t)t * DD;
    float part = 0.f;
    for (int i = 0; i < 128; ++i) {
        int k = sl * 128 + i;
        part += x[k] * Wg[(size_t)k * EE + e];
    }
    __shared__ float red[16][17];
    red[sl][e] = part;
    __syncthreads();
    if (threadIdx.x == 0) {
        float lg[16], pr[16];
        for (int ee = 0; ee < 16; ++ee) {
            float s = 0.f;
            for (int q = 0; q < 16; ++q) s += red[q][ee];
            lg[ee] = s;
        }
        float mx = lg[0];
        for (int ee = 1; ee < 16; ++ee) mx = fmaxf(mx, lg[ee]);
        float sum = 0.f;
        for (int ee = 0; ee < 16; ++ee) { pr[ee] = expf(lg[ee] - mx); sum += pr[ee]; }
        float isum = 1.0f / sum;
        for (int ee = 0; ee < 16; ++ee) pr[ee] *= isum;
        unsigned used = 0;
        int sel[NTOP]; float rw[NTOP]; float s6 = 0.f;
        for (int kk = 0; kk < NTOP; ++kk) {
            int best = 0; float bv = -1e30f;
            for (int ee = 0; ee < 16; ++ee) {
                if (used & (1u << ee)) continue;
                float sc = pr[ee] + bias[ee];
                if (sc > bv) { bv = sc; best = ee; }
            }
            used |= 1u << best;
            sel[kk] = best; rw[kk] = pr[best]; s6 += pr[best];
        }
        float inv6 = 1.0f / fmaxf(s6, 1e-12f);
        for (int kk = 0; kk < NTOP; ++kk) {
            int ee = sel[kk];
            int pos = atomicAdd(&cnt[ee], 1);
            list[ee*CAP + pos] = (t << 3) | kk;
            wts[ee*CAP + pos] = rw[kk] * inv6;
        }
    }
}

// ---------------- Final: out = h2 + shared + sum_kk routed ------------------
__global__ __launch_bounds__(256) void k_final(
    const float* __restrict__ h2, const float* __restrict__ yb,
    const u16* __restrict__ rb, float* __restrict__ out)
{
    int id = blockIdx.x * 256 + threadIdx.x;     // T*D/4
    size_t i4 = (size_t)id * 4;
    int t = id >> 9;
    int d = (id & 511) * 4;
    f32x4 acc = *(const f32x4*)(h2 + i4);
    f32x4 y = *(const f32x4*)(yb + i4);
    acc += y;
    #pragma unroll
    for (int kk = 0; kk < NTOP; ++kk) {
        s16x4 rv = *(const s16x4*)(rb + ((size_t)t*NTOP + kk)*DD + d);
        acc[0] += b2f((u16)rv[0]); acc[1] += b2f((u16)rv[1]);
        acc[2] += b2f((u16)rv[2]); acc[3] += b2f((u16)rv[3]);
    }
    *(f32x4*)(out + i4) = acc;
}

extern "C" void kernel_launch(void* const* d_in, const int* in_sizes, int n_in,
                              void* d_out, int out_size, void* d_ws, size_t ws_size,
                              hipStream_t stream)
{
    (void)in_sizes; (void)n_in; (void)out_size; (void)ws_size;
    const float* hidden = (const float*)d_in[0];
    const float* cosb   = (const float*)d_in[1];
    const float* sinb   = (const float*)d_in[2];
    const float* ln1    = (const float*)d_in[3];
    const float* ln2    = (const float*)d_in[4];
    const float* Wq     = (const float*)d_in[5];
    const float* Wk     = (const float*)d_in[6];
    const float* Wv     = (const float*)d_in[7];
    const float* Wo     = (const float*)d_in[8];
    const float* Wgate  = (const float*)d_in[9];
    const float* cbias  = (const float*)d_in[10];
    const float* Wg     = (const float*)d_in[11];
    const float* Wu     = (const float*)d_in[12];
    const float* Wd     = (const float*)d_in[13];
    const float* Wgs    = (const float*)d_in[14];
    const float* Wus    = (const float*)d_in[15];
    const float* Wds    = (const float*)d_in[16];
    float* out = (float*)d_out;

    char* ws = (char*)d_ws;
    size_t off = 0;
    auto alloc = [&](size_t bytes) {
        void* p = ws + off;
        off = (off + bytes + 255) & ~(size_t)255;
        return p;
    };
    // Pre-transposed bf16 weights
    u16* WqkvTh = (u16*)alloc((size_t)3072*2048*2);
    u16* WqkvTl = (u16*)alloc((size_t)3072*2048*2);
    u16* WoTh   = (u16*)alloc((size_t)2048*2048*2);
    u16* WoTl   = (u16*)alloc((size_t)2048*2048*2);
    u16* WgsT   = (u16*)alloc((size_t)2048*2048*2);
    u16* WusT   = (u16*)alloc((size_t)2048*2048*2);
    u16* WdsT   = (u16*)alloc((size_t)2048*2048*2);
    u16* WgT    = (u16*)alloc((size_t)EE*II*DD*2);
    u16* WuT    = (u16*)alloc((size_t)EE*II*DD*2);
    u16* WdT    = (u16*)alloc((size_t)EE*DD*II*2);
    // Activations
    u16*   x1h  = (u16*)  alloc((size_t)TT*DD*2);
    u16*   x1l  = (u16*)  alloc((size_t)TT*DD*2);
    float* qkvf = (float*)alloc((size_t)TT*3072*4);
    u16*   qh   = (u16*)  alloc((size_t)TT*HH*HDD*2);
    u16*   ql   = (u16*)  alloc((size_t)TT*HH*HDD*2);
    u16*   kh   = (u16*)  alloc((size_t)TT*HKK*HDD*2);
    u16*   kl   = (u16*)  alloc((size_t)TT*HKK*HDD*2);
    u16*   vth  = (u16*)  alloc((size_t)TT*HKK*HDD*2);
    u16*   vtl  = (u16*)  alloc((size_t)TT*HKK*HDD*2);
    u16*   aoh  = (u16*)  alloc((size_t)TT*HH*HDD*2);
    u16*   aol  = (u16*)  alloc((size_t)TT*HH*HDD*2);
    float* h2   = (float*)alloc((size_t)TT*DD*4);
    u16*   x2   = (u16*)  alloc((size_t)TT*DD*2);
    float* x2f  = (float*)alloc((size_t)TT*DD*4);
    int*   cnt  = (int*)  alloc(256);
    int*   lst  = (int*)  alloc((size_t)EE*CAP*4);
    float* wts  = (float*)alloc((size_t)EE*CAP*4);
    u16*   hE   = (u16*)  alloc((size_t)EE*CAP*II*2);
    u16*   rbuf = (u16*)  alloc((size_t)TT*NTOP*DD*2);
    // Aliases (lifetimes disjoint):
    u16*   hs   = x1h;            // [TT][ISS] bf16 = 8MB, x1h dead after QKV
    float* ybuf = qkvf;           // [TT][DD] f32 = 16MB, qkvf dead after splits

    // ---- Weight prep (transpose + bf16 convert [+ split]) ----
    k_prep<true ><<<dim3(64,64,1), 256, 0, stream>>>(Wq, WqkvTh, WqkvTl, 2048, 2048);
    k_prep<true ><<<dim3(16,64,1), 256, 0, stream>>>(Wk, WqkvTh + (size_t)2048*2048, WqkvTl + (size_t)2048*2048, 2048, 512);
    k_prep<true ><<<dim3(16,64,1), 256, 0, stream>>>(Wv, WqkvTh + (size_t)2560*2048, WqkvTl + (size_t)2560*2048, 2048, 512);
    k_prep<true ><<<dim3(64,64,1), 256, 0, stream>>>(Wo, WoTh, WoTl, 2048, 2048);
    k_prep<false><<<dim3(64,64,1), 256, 0, stream>>>(Wgs, WgsT, nullptr, 2048, 2048);
    k_prep<false><<<dim3(64,64,1), 256, 0, stream>>>(Wus, WusT, nullptr, 2048, 2048);
    k_prep<false><<<dim3(64,64,1), 256, 0, stream>>>(Wds, WdsT, nullptr, 2048, 2048);
    k_prep<false><<<dim3(32,64,EE), 256, 0, stream>>>(Wg, WgT, nullptr, 2048, 1024);
    k_prep<false><<<dim3(32,64,EE), 256, 0, stream>>>(Wu, WuT, nullptr, 2048, 1024);
    k_prep<false><<<dim3(64,32,EE), 256, 0, stream>>>(Wd, WdT, nullptr, 1024, 2048);

    // ---- Attention path (split-bf16 high precision) ----
    k_rmsnorm_split<<<TT, 256, 0, stream>>>(hidden, ln1, x1h, x1l);
    k_gemm_hi<2><<<dim3(24,16), 256, 0, stream>>>(x1h, x1l, WqkvTh, WqkvTl, qkvf, nullptr, TT, 3072, DD);
    k_rope_f32<<<(TT*20*64)/256, 256, 0, stream>>>(qkvf, cosb, sinb);
    k_split_s<<<(TT*2048/8)/256, 256, 0, stream>>>(qkvf, 3072, 2048, qh, ql);
    k_split_s<<<(TT*512/8)/256, 256, 0, stream>>>(qkvf + 2048, 3072, 512, kh, kl);
    k_split_vt<<<(TT*HKK*HDD/8)/256, 256, 0, stream>>>(qkvf, vth, vtl);
    k_attn_hi<<<dim3(SS/64, BB*HH), 256, 0, stream>>>(qh, ql, kh, kl, vth, vtl, aoh, aol);
    k_gemm_hi<1><<<dim3(16,16), 256, 0, stream>>>(aoh, aol, WoTh, WoTl, h2, hidden, TT, DD, HH*HDD);

    // ---- MoE path ----
    k_rmsnorm_bf<<<TT, 256, 0, stream>>>(h2, ln2, x2, x2f);
    hipMemsetAsync(cnt, 0, 256, stream);
    k_router<<<TT, 256, 0, stream>>>(x2f, Wgate, cbias, cnt, lst, wts);
    k_glu<false><<<dim3(ISS/64, TT/128, 1), 256, 0, stream>>>(x2, WgsT, WusT, hs, nullptr, nullptr, TT, ISS, DD);
    k_gemm<2><<<dim3(16,16), 256, 0, stream>>>(hs, WdsT, ybuf, TT, DD, ISS);
    k_glu<true><<<dim3(II/64, CAP/128, EE), 256, 0, stream>>>(x2, WgT, WuT, hE, lst, cnt, CAP, II, DD);
    k_down_scatter<<<dim3(DD/128, CAP/128, EE), 256, 0, stream>>>(hE, WdT, rbuf, lst, wts, cnt, DD, II);
    k_final<<<(TT*DD/4)/256, 256, 0, stream>>>(h2, ybuf, rbuf, out);
}

// Round 6
// 1092.695 us; speedup vs baseline: 1.8295x; 1.0273x over previous
//
#include <hip/hip_runtime.h>
#include <cstdint>

typedef unsigned short u16;
typedef __attribute__((ext_vector_type(8))) short short8;
typedef __attribute__((ext_vector_type(4))) short s16x4;
typedef __attribute__((ext_vector_type(4))) float f32x4;

#define MFMA_16x16x32(a,b,c) __builtin_amdgcn_mfma_f32_16x16x32_bf16(a,b,c,0,0,0)

// async global->LDS, 16B per lane, wave covers 1024B (16 rows of a [*][32] bf16 tile)
#define GLDS16(lds, g) __builtin_amdgcn_global_load_lds( \
    (const __attribute__((address_space(1))) unsigned int*)(g), \
    (__attribute__((address_space(3))) unsigned int*)(lds), 16, 0, 0)

#define BB 2
#define SS 1024
#define DD 2048
#define HH 16
#define HKK 4
#define HDD 128
#define EE 16
#define NTOP 6
#define II 1024
#define ISS 2048
#define TT 2048
#define CAP 2048

__device__ __forceinline__ u16 f2b(float f) {
    union { float f; uint32_t u; } v; v.f = f;
    uint32_t r = v.u + 0x7FFFu + ((v.u >> 16) & 1u);
    return (u16)(r >> 16);
}
__device__ __forceinline__ float b2f(u16 h) {
    union { uint32_t u; float f; } v; v.u = ((uint32_t)h) << 16;
    return v.f;
}
__device__ __forceinline__ void fsplit(float f, u16& hi, u16& lo) {
    u16 h = f2b(f);
    hi = h;
    lo = f2b(f - b2f(h));
}

// ---------- Prep: transpose+convert W f32 [R][C] -> bf16 [C][R] (hi[,lo]) ---
template<bool SPLIT>
__global__ __launch_bounds__(256) void k_prep(
    const float* __restrict__ In, u16* __restrict__ Oh, u16* __restrict__ Ol,
    int R, int C)
{
    const size_t zoff = (size_t)blockIdx.z * R * C;
    In += zoff; Oh += zoff; if (SPLIT) Ol += zoff;
    const int r0 = blockIdx.y * 32, c0 = blockIdx.x * 32;
    __shared__ float tile[32][33];
    const int tx = threadIdx.x & 31, ty = threadIdx.x >> 5;
    #pragma unroll
    for (int i = 0; i < 4; ++i)
        tile[ty + i*8][tx] = In[(size_t)(r0 + ty + i*8)*C + c0 + tx];
    __syncthreads();
    const int c = threadIdx.x >> 3, rs = (threadIdx.x & 7) * 4;
    s16x4 hv, lv;
    #pragma unroll
    for (int j = 0; j < 4; ++j) {
        float f = tile[rs + j][c];
        u16 hb = f2b(f);
        hv[j] = (short)hb;
        if (SPLIT) lv[j] = (short)f2b(f - b2f(hb));
        else lv[j] = 0;
    }
    *(s16x4*)(Oh + (size_t)(c0 + c)*R + r0 + rs) = hv;
    if (SPLIT) *(s16x4*)(Ol + (size_t)(c0 + c)*R + r0 + rs) = lv;
}

// ---------------- RMSNorm f32 in -> split bf16 (hi,lo) ----------------------
__global__ __launch_bounds__(256) void k_rmsnorm_split(
    const float* __restrict__ X, const float* __restrict__ Wt,
    u16* __restrict__ Oh, u16* __restrict__ Ol)
{
    const int t = blockIdx.x;
    const float* x = X + (size_t)t * DD;
    const int base = threadIdx.x * 8;
    f32x4 v0 = *(const f32x4*)(x + base);
    f32x4 v1 = *(const f32x4*)(x + base + 4);
    float ss = 0.f;
    #pragma unroll
    for (int j = 0; j < 4; ++j) ss += v0[j]*v0[j] + v1[j]*v1[j];
    #pragma unroll
    for (int o = 1; o < 64; o <<= 1) ss += __shfl_xor(ss, o);
    __shared__ float red[4];
    if ((threadIdx.x & 63) == 0) red[threadIdx.x >> 6] = ss;
    __syncthreads();
    float tot = red[0] + red[1] + red[2] + red[3];
    float inv = rsqrtf(tot * (1.0f/DD) + 1e-6f);
    f32x4 w0 = *(const f32x4*)(Wt + base);
    f32x4 w1 = *(const f32x4*)(Wt + base + 4);
    u16* oh = Oh + (size_t)t*DD + base;
    u16* ol = Ol + (size_t)t*DD + base;
    #pragma unroll
    for (int j = 0; j < 4; ++j) {
        float y0 = v0[j]*inv*w0[j];
        float y1 = v1[j]*inv*w1[j];
        fsplit(y0, oh[j],   ol[j]);
        fsplit(y1, oh[4+j], ol[4+j]);
    }
}

// ---------------- RMSNorm f32 in -> bf16 + f32 ------------------------------
__global__ __launch_bounds__(256) void k_rmsnorm_bf(
    const float* __restrict__ X, const float* __restrict__ Wt,
    u16* __restrict__ Ob, float* __restrict__ Of)
{
    const int t = blockIdx.x;
    const float* x = X + (size_t)t * DD;
    const int base = threadIdx.x * 8;
    f32x4 v0 = *(const f32x4*)(x + base);
    f32x4 v1 = *(const f32x4*)(x + base + 4);
    float ss = 0.f;
    #pragma unroll
    for (int j = 0; j < 4; ++j) ss += v0[j]*v0[j] + v1[j]*v1[j];
    #pragma unroll
    for (int o = 1; o < 64; o <<= 1) ss += __shfl_xor(ss, o);
    __shared__ float red[4];
    if ((threadIdx.x & 63) == 0) red[threadIdx.x >> 6] = ss;
    __syncthreads();
    float tot = red[0] + red[1] + red[2] + red[3];
    float inv = rsqrtf(tot * (1.0f/DD) + 1e-6f);
    f32x4 w0 = *(const f32x4*)(Wt + base);
    f32x4 w1 = *(const f32x4*)(Wt + base + 4);
    u16* ob = Ob + (size_t)t*DD + base;
    float* of = Of + (size_t)t*DD + base;
    #pragma unroll
    for (int j = 0; j < 4; ++j) {
        float y0 = v0[j]*inv*w0[j];
        float y1 = v1[j]*inv*w1[j];
        ob[j] = f2b(y0); ob[4+j] = f2b(y1);
        of[j] = y0;      of[4+j] = y1;
    }
}

// ------- High-precision GEMM: C = (Ah+Al) @ (Bh+Bl)^T, pre-split bf16 -------
// 2-phase prefetch, dbuf LDS. EPI 1: f32 + residual; 2: f32
template<int EPI>
__global__ __launch_bounds__(256) void k_gemm_hi(
    const u16* __restrict__ Ah, const u16* __restrict__ Al,
    const u16* __restrict__ Bth, const u16* __restrict__ Btl,
    float* __restrict__ C, const float* __restrict__ Res,
    int M, int N, int K)
{
    __shared__ u16 Ash[2][128][32];
    __shared__ u16 Asl[2][128][32];
    __shared__ u16 Bsh[2][128][32];
    __shared__ u16 Bsl[2][128][32];
    const int tid = threadIdx.x;
    const int lane = tid & 63;
    const int w = tid >> 6;
    const int m0 = blockIdx.y * 128, n0 = blockIdx.x * 128;
    const int wm = (w >> 1) * 64, wn = (w & 1) * 64;
    const int l15 = lane & 15, lhi = lane >> 4;
    f32x4 acc[4][4];
    #pragma unroll
    for (int a = 0; a < 4; ++a)
        #pragma unroll
        for (int b = 0; b < 4; ++b) acc[a][b] = 0;

    const int gr = w*32 + (lane >> 2);
    const int gc = (lane & 3) * 8;
    const u16* ahP0 = Ah  + (size_t)(m0 + gr) * K + gc;
    const u16* alP0 = Al  + (size_t)(m0 + gr) * K + gc;
    const u16* bhP0 = Bth + (size_t)(n0 + gr) * K + gc;
    const u16* blP0 = Btl + (size_t)(n0 + gr) * K + gc;
    const size_t r16 = (size_t)16 * K;

    // prologue: stage tile 0 into buf 0
    GLDS16(&Ash[0][w*32][0],      ahP0);
    GLDS16(&Ash[0][w*32 + 16][0], ahP0 + r16);
    GLDS16(&Asl[0][w*32][0],      alP0);
    GLDS16(&Asl[0][w*32 + 16][0], alP0 + r16);
    GLDS16(&Bsh[0][w*32][0],      bhP0);
    GLDS16(&Bsh[0][w*32 + 16][0], bhP0 + r16);
    GLDS16(&Bsl[0][w*32][0],      blP0);
    GLDS16(&Bsl[0][w*32 + 16][0], blP0 + r16);
    __syncthreads();

    int cur = 0;
    for (int k0 = 0; k0 < K; k0 += 32) {
        const int nxt = k0 + 32;
        if (nxt < K) {
            GLDS16(&Ash[cur^1][w*32][0],      ahP0 + nxt);
            GLDS16(&Ash[cur^1][w*32 + 16][0], ahP0 + r16 + nxt);
            GLDS16(&Asl[cur^1][w*32][0],      alP0 + nxt);
            GLDS16(&Asl[cur^1][w*32 + 16][0], alP0 + r16 + nxt);
            GLDS16(&Bsh[cur^1][w*32][0],      bhP0 + nxt);
            GLDS16(&Bsh[cur^1][w*32 + 16][0], bhP0 + r16 + nxt);
            GLDS16(&Bsl[cur^1][w*32][0],      blP0 + nxt);
            GLDS16(&Bsl[cur^1][w*32 + 16][0], blP0 + r16 + nxt);
        }
        short8 afh[4], afl[4], bfh[4], bfl[4];
        #pragma unroll
        for (int i = 0; i < 4; ++i) {
            afh[i] = *(const short8*)&Ash[cur][wm + i*16 + l15][lhi*8];
            afl[i] = *(const short8*)&Asl[cur][wm + i*16 + l15][lhi*8];
            bfh[i] = *(const short8*)&Bsh[cur][wn + i*16 + l15][lhi*8];
            bfl[i] = *(const short8*)&Bsl[cur][wn + i*16 + l15][lhi*8];
        }
        #pragma unroll
        for (int a = 0; a < 4; ++a)
            #pragma unroll
            for (int b = 0; b < 4; ++b) {
                acc[a][b] = MFMA_16x16x32(afh[a], bfh[b], acc[a][b]);
                acc[a][b] = MFMA_16x16x32(afh[a], bfl[b], acc[a][b]);
                acc[a][b] = MFMA_16x16x32(afl[a], bfh[b], acc[a][b]);
            }
        __syncthreads();
        cur ^= 1;
    }
    #pragma unroll
    for (int a = 0; a < 4; ++a)
      #pragma unroll
      for (int b = 0; b < 4; ++b)
        #pragma unroll
        for (int r = 0; r < 4; ++r) {
            int m = m0 + wm + a*16 + lhi*4 + r;
            int n = n0 + wn + b*16 + l15;
            size_t off = (size_t)m * N + n;
            float v = acc[a][b][r];
            if (EPI == 1) C[off] = v + Res[off];
            else C[off] = v;
        }
}

// ---------------- Dense GEMM: C(MxN) = A_bf16 @ Bt_bf16^T, 2-phase ----------
// EPI 0: bf16 store; 2: f32 store
template<int EPI>
__global__ __launch_bounds__(256) void k_gemm(
    const u16* __restrict__ A, const u16* __restrict__ Bt,
    void* __restrict__ C, int M, int N, int K)
{
    __shared__ u16 As[2][128][32];
    __shared__ u16 Bs[2][128][32];
    const int tid = threadIdx.x;
    const int lane = tid & 63;
    const int w = tid >> 6;
    const int m0 = blockIdx.y * 128, n0 = blockIdx.x * 128;
    const int wm = (w >> 1) * 64, wn = (w & 1) * 64;
    const int l15 = lane & 15, lhi = lane >> 4;
    f32x4 acc[4][4];
    #pragma unroll
    for (int a = 0; a < 4; ++a)
        #pragma unroll
        for (int b = 0; b < 4; ++b) acc[a][b] = 0;

    const int gr = w*32 + (lane >> 2);
    const int gc = (lane & 3) * 8;
    const u16* aP0 = A  + (size_t)(m0 + gr) * K + gc;
    const u16* bP0 = Bt + (size_t)(n0 + gr) * K + gc;
    const size_t r16 = (size_t)16 * K;

    GLDS16(&As[0][w*32][0],      aP0);
    GLDS16(&As[0][w*32 + 16][0], aP0 + r16);
    GLDS16(&Bs[0][w*32][0],      bP0);
    GLDS16(&Bs[0][w*32 + 16][0], bP0 + r16);
    __syncthreads();

    int cur = 0;
    for (int k0 = 0; k0 < K; k0 += 32) {
        const int nxt = k0 + 32;
        if (nxt < K) {
            GLDS16(&As[cur^1][w*32][0],      aP0 + nxt);
            GLDS16(&As[cur^1][w*32 + 16][0], aP0 + r16 + nxt);
            GLDS16(&Bs[cur^1][w*32][0],      bP0 + nxt);
            GLDS16(&Bs[cur^1][w*32 + 16][0], bP0 + r16 + nxt);
        }
        short8 af[4], bf[4];
        #pragma unroll
        for (int i = 0; i < 4; ++i) af[i] = *(const short8*)&As[cur][wm + i*16 + l15][lhi*8];
        #pragma unroll
        for (int i = 0; i < 4; ++i) bf[i] = *(const short8*)&Bs[cur][wn + i*16 + l15][lhi*8];
        #pragma unroll
        for (int a = 0; a < 4; ++a)
            #pragma unroll
            for (int b = 0; b < 4; ++b)
                acc[a][b] = MFMA_16x16x32(af[a], bf[b], acc[a][b]);
        __syncthreads();
        cur ^= 1;
    }
    #pragma unroll
    for (int a = 0; a < 4; ++a)
      #pragma unroll
      for (int b = 0; b < 4; ++b)
        #pragma unroll
        for (int r = 0; r < 4; ++r) {
            int m = m0 + wm + a*16 + lhi*4 + r;
            int n = n0 + wn + b*16 + l15;
            size_t off = (size_t)m * N + n;
            float v = acc[a][b][r];
            if (EPI == 0) ((u16*)C)[off] = f2b(v);
            else ((float*)C)[off] = v;
        }
}

// ---------------- Fused GLU GEMM: h = silu(A@W1) * (A@W2), 2-phase ----------
template<bool GATHER>
__global__ __launch_bounds__(256) void k_glu(
    const u16* __restrict__ Xb, const u16* __restrict__ W1t,
    const u16* __restrict__ W2t, u16* __restrict__ Hout,
    const int* __restrict__ list, const int* __restrict__ cntp,
    int M, int NE, int K)
{
    const int e = GATHER ? blockIdx.z : 0;
    const int cnt = GATHER ? cntp[e] : M;
    const int m0 = blockIdx.y * 128;
    if (m0 >= cnt) return;
    const int n0 = blockIdx.x * 64;
    const u16* w1 = W1t + (size_t)e * NE * K;
    const u16* w2 = W2t + (size_t)e * NE * K;
    u16* hout = Hout + (size_t)e * CAP * NE;
    const int* lst = GATHER ? (list + e * CAP) : nullptr;

    __shared__ u16 As[2][128][32];
    __shared__ u16 B1s[2][64][32];
    __shared__ u16 B2s[2][64][32];

    const int tid = threadIdx.x, lane = tid & 63, w = tid >> 6;
    const int wm = (w >> 1) * 64, wn = (w & 1) * 32;
    const int l15 = lane & 15, lhi = lane >> 4;
    f32x4 acc1[4][2], acc2[4][2];
    #pragma unroll
    for (int a = 0; a < 4; ++a)
        #pragma unroll
        for (int j = 0; j < 2; ++j) { acc1[a][j] = 0; acc2[a][j] = 0; }

    const int gr  = w*32 + (lane >> 2);
    const int grB = w*16 + (lane >> 2);
    const int gc  = (lane & 3) * 8;
    int arow0, arow1;
    if (GATHER) {
        int mr0 = m0 + gr, mr1 = m0 + gr + 16;
        arow0 = (mr0 < cnt) ? (lst[mr0] >> 3) : 0;
        arow1 = (mr1 < cnt) ? (lst[mr1] >> 3) : 0;
    } else { arow0 = m0 + gr; arow1 = m0 + gr + 16; }
    const u16* aP0 = Xb + (size_t)arow0 * K + gc;
    const u16* aP1 = Xb + (size_t)arow1 * K + gc;
    const u16* b1P = w1 + (size_t)(n0 + grB) * K + gc;
    const u16* b2P = w2 + (size_t)(n0 + grB) * K + gc;

    GLDS16(&As[0][w*32][0],      aP0);
    GLDS16(&As[0][w*32 + 16][0], aP1);
    GLDS16(&B1s[0][w*16][0],     b1P);
    GLDS16(&B2s[0][w*16][0],     b2P);
    __syncthreads();

    int cur = 0;
    for (int k0 = 0; k0 < K; k0 += 32) {
        const int nxt = k0 + 32;
        if (nxt < K) {
            GLDS16(&As[cur^1][w*32][0],      aP0 + nxt);
            GLDS16(&As[cur^1][w*32 + 16][0], aP1 + nxt);
            GLDS16(&B1s[cur^1][w*16][0],     b1P + nxt);
            GLDS16(&B2s[cur^1][w*16][0],     b2P + nxt);
        }
        short8 af[4], b1[2], b2[2];
        #pragma unroll
        for (int i = 0; i < 4; ++i) af[i] = *(const short8*)&As[cur][wm + i*16 + l15][lhi*8];
        #pragma unroll
        for (int j = 0; j < 2; ++j) {
            b1[j] = *(const short8*)&B1s[cur][wn + j*16 + l15][lhi*8];
            b2[j] = *(const short8*)&B2s[cur][wn + j*16 + l15][lhi*8];
        }
        #pragma unroll
        for (int a = 0; a < 4; ++a)
            #pragma unroll
            for (int j = 0; j < 2; ++j) {
                acc1[a][j] = MFMA_16x16x32(af[a], b1[j], acc1[a][j]);
                acc2[a][j] = MFMA_16x16x32(af[a], b2[j], acc2[a][j]);
            }
        __syncthreads();
        cur ^= 1;
    }
    #pragma unroll
    for (int a = 0; a < 4; ++a)
      #pragma unroll
      for (int j = 0; j < 2; ++j)
        #pragma unroll
        for (int r = 0; r < 4; ++r) {
            int m = m0 + wm + a*16 + lhi*4 + r;
            if (m < cnt) {
                int n = n0 + wn + j*16 + l15;
                float g = acc1[a][j][r], u = acc2[a][j][r];
                float hval = g / (1.0f + __expf(-g)) * u;
                hout[(size_t)m * NE + n] = f2b(hval);
            }
        }
}

// ---------------- Routed down GEMM with scatter + weight, 2-phase -----------
__global__ __launch_bounds__(256) void k_down_scatter(
    const u16* __restrict__ Hb, const u16* __restrict__ WdTt,
    u16* __restrict__ Rbuf, const int* __restrict__ list,
    const float* __restrict__ wts, const int* __restrict__ cntp,
    int N, int K)
{
    const int e = blockIdx.z;
    const int cnt = cntp[e];
    const int m0 = blockIdx.y * 128;
    if (m0 >= cnt) return;
    const int n0 = blockIdx.x * 128;
    const u16* A  = Hb   + (size_t)e * CAP * K;
    const u16* Bt = WdTt + (size_t)e * N * K;

    __shared__ u16 As[2][128][32];
    __shared__ u16 Bs[2][128][32];
    const int tid = threadIdx.x, lane = tid & 63, w = tid >> 6;
    const int wm = (w >> 1) * 64, wn = (w & 1) * 64;
    const int l15 = lane & 15, lhi = lane >> 4;
    f32x4 acc[4][4];
    #pragma unroll
    for (int a = 0; a < 4; ++a)
        #pragma unroll
        for (int b = 0; b < 4; ++b) acc[a][b] = 0;

    const int gr = w*32 + (lane >> 2);
    const int gc = (lane & 3) * 8;
    const u16* aP0 = A  + (size_t)(m0 + gr) * K + gc;
    const u16* bP0 = Bt + (size_t)(n0 + gr) * K + gc;
    const size_t r16 = (size_t)16 * K;

    GLDS16(&As[0][w*32][0],      aP0);
    GLDS16(&As[0][w*32 + 16][0], aP0 + r16);
    GLDS16(&Bs[0][w*32][0],      bP0);
    GLDS16(&Bs[0][w*32 + 16][0], bP0 + r16);
    __syncthreads();

    int cur = 0;
    for (int k0 = 0; k0 < K; k0 += 32) {
        const int nxt = k0 + 32;
        if (nxt < K) {
            GLDS16(&As[cur^1][w*32][0],      aP0 + nxt);
            GLDS16(&As[cur^1][w*32 + 16][0], aP0 + r16 + nxt);
            GLDS16(&Bs[cur^1][w*32][0],      bP0 + nxt);
            GLDS16(&Bs[cur^1][w*32 + 16][0], bP0 + r16 + nxt);
        }
        short8 af[4], bf[4];
        #pragma unroll
        for (int i = 0; i < 4; ++i) af[i] = *(const short8*)&As[cur][wm + i*16 + l15][lhi*8];
        #pragma unroll
        for (int i = 0; i < 4; ++i) bf[i] = *(const short8*)&Bs[cur][wn + i*16 + l15][lhi*8];
        #pragma unroll
        for (int a = 0; a < 4; ++a)
            #pragma unroll
            for (int b = 0; b < 4; ++b)
                acc[a][b] = MFMA_16x16x32(af[a], bf[b], acc[a][b]);
        __syncthreads();
        cur ^= 1;
    }
    #pragma unroll
    for (int a = 0; a < 4; ++a)
      #pragma unroll
      for (int b = 0; b < 4; ++b)
        #pragma unroll
        for (int r = 0; r < 4; ++r) {
            int m = m0 + wm + a*16 + lhi*4 + r;
            if (m < cnt) {
                int n = n0 + wn + b*16 + l15;
                int enc = list[e*CAP + m];
                float wgt = wts[e*CAP + m];
                int tok = enc >> 3, kk = enc & 7;
                Rbuf[((size_t)tok*NTOP + kk)*N + n] = f2b(acc[a][b][r] * wgt);
            }
        }
}

// ---------------- Fused RoPE + split for q,k (f32 in -> hi/lo bf16) ---------
__global__ __launch_bounds__(256) void k_rope_split(
    const float* __restrict__ QKV,
    const float* __restrict__ Cs, const float* __restrict__ Sn,
    u16* __restrict__ Qh, u16* __restrict__ Ql,
    u16* __restrict__ Kh, u16* __restrict__ Kl)
{
    int id = blockIdx.x * 256 + threadIdx.x;   // TT * 20 * 64
    int pr = id & 63;
    int rest = id >> 6;
    int hh = rest % 20;
    int tok = rest / 20;
    if (tok >= TT) return;
    int d0 = pr * 2;
    float c0 = Cs[(size_t)tok*HDD + d0];
    float c1 = Cs[(size_t)tok*HDD + d0 + 1];
    float s0 = Sn[(size_t)tok*HDD + d0];
    float s1 = Sn[(size_t)tok*HDD + d0 + 1];
    const float* p = QKV + (size_t)tok*3072 + (hh < HH ? hh*HDD : 2048 + (hh - HH)*HDD);
    float x0 = p[d0], x1 = p[d0+1];
    float y0 = x0*c0 - x1*s0;
    float y1 = x1*c1 + x0*s1;
    u16 *oh, *ol;
    size_t ooff;
    if (hh < HH) { ooff = ((size_t)tok*HH + hh)*HDD + d0; oh = Qh; ol = Ql; }
    else         { ooff = ((size_t)tok*HKK + (hh - HH))*HDD + d0; oh = Kh; ol = Kl; }
    fsplit(y0, oh[ooff],     ol[ooff]);
    fsplit(y1, oh[ooff + 1], ol[ooff + 1]);
}

// ---------------- V from qkvf -> split V^T (b,hk,d,s) -----------------------
__global__ __launch_bounds__(256) void k_split_vt(
    const float* __restrict__ QKV, u16* __restrict__ Vth, u16* __restrict__ Vtl)
{
    int id = blockIdx.x * 256 + threadIdx.x;   // TT*HKK*HDD/8
    int oid = id * 8;
    int s0 = oid & (SS - 1);
    int r = oid >> 10;
    int d = r & (HDD - 1);
    int bh = r >> 7;
    int b = bh >> 2, hk = bh & 3;
    #pragma unroll
    for (int j = 0; j < 8; ++j) {
        int s = s0 + j;
        float v = QKV[(size_t)(b*SS + s)*3072 + 2560 + hk*HDD + d];
        fsplit(v, Vth[oid + j], Vtl[oid + j]);
    }
}

// ---------------- Flash attention, split-bf16 precision ---------------------
__global__ __launch_bounds__(256) void k_attn_hi(
    const u16* __restrict__ Qh, const u16* __restrict__ Ql,
    const u16* __restrict__ Kh, const u16* __restrict__ Kl,
    const u16* __restrict__ Vth, const u16* __restrict__ Vtl,
    u16* __restrict__ Oh, u16* __restrict__ Ol)
{
    const int tid = threadIdx.x;
    const int lane = tid & 63;
    const int w = tid >> 6;
    const int q0 = blockIdx.x * 64;
    const int b = blockIdx.y >> 4;
    const int h = blockIdx.y & 15;
    const int hk = h >> 2;
    const int l15 = lane & 15, lhi = lane >> 4;

    __shared__ u16 Ksh[32][136];
    __shared__ u16 Ksl[32][136];
    __shared__ u16 Vsh[128][40];
    __shared__ u16 Vsl[128][40];
    __shared__ u16 Psh[4][16][40];
    __shared__ u16 Psl[4][16][40];

    short8 qfh[4], qfl[4];
    {
        const int qrow = q0 + w*16 + l15;
        const u16* qph = Qh + ((size_t)(b*SS + qrow)*HH + h)*HDD;
        const u16* qpl = Ql + ((size_t)(b*SS + qrow)*HH + h)*HDD;
        #pragma unroll
        for (int c = 0; c < 4; ++c) {
            qfh[c] = *(const short8*)(qph + c*32 + lhi*8);
            qfl[c] = *(const short8*)(qpl + c*32 + lhi*8);
        }
    }

    f32x4 oacc[8];
    #pragma unroll
    for (int ch = 0; ch < 8; ++ch) oacc[ch] = 0;
    float m_r[4] = {-1e30f, -1e30f, -1e30f, -1e30f};
    float l_r[4] = {0.f, 0.f, 0.f, 0.f};

    const int nkt = (q0 + 64) >> 5;
    const int kr = tid >> 3, kc = (tid & 7) * 16;
    const int vd = tid >> 1, vj = (tid & 1) * 16;

    for (int kt = 0; kt < nkt; ++kt) {
        __syncthreads();
        {
            size_t koff = ((size_t)(b*SS + kt*32 + kr)*HKK + hk)*HDD + kc;
            *(short8*)&Ksh[kr][kc]     = *(const short8*)(Kh + koff);
            *(short8*)&Ksh[kr][kc + 8] = *(const short8*)(Kh + koff + 8);
            *(short8*)&Ksl[kr][kc]     = *(const short8*)(Kl + koff);
            *(short8*)&Ksl[kr][kc + 8] = *(const short8*)(Kl + koff + 8);
        }
        {
            size_t voff = ((size_t)(b*HKK + hk)*HDD + vd)*SS + kt*32 + vj;
            *(short8*)&Vsh[vd][vj]     = *(const short8*)(Vth + voff);
            *(short8*)&Vsh[vd][vj + 8] = *(const short8*)(Vth + voff + 8);
            *(short8*)&Vsl[vd][vj]     = *(const short8*)(Vtl + voff);
            *(short8*)&Vsl[vd][vj + 8] = *(const short8*)(Vtl + voff + 8);
        }
        __syncthreads();

        f32x4 s0 = 0, s1 = 0;
        #pragma unroll
        for (int c = 0; c < 4; ++c) {
            short8 kh0 = *(const short8*)&Ksh[l15][c*32 + lhi*8];
            short8 kl0 = *(const short8*)&Ksl[l15][c*32 + lhi*8];
            short8 kh1 = *(const short8*)&Ksh[16 + l15][c*32 + lhi*8];
            short8 kl1 = *(const short8*)&Ksl[16 + l15][c*32 + lhi*8];
            s0 = MFMA_16x16x32(qfh[c], kh0, s0);
            s0 = MFMA_16x16x32(qfh[c], kl0, s0);
            s0 = MFMA_16x16x32(qfl[c], kh0, s0);
            s1 = MFMA_16x16x32(qfh[c], kh1, s1);
            s1 = MFMA_16x16x32(qfh[c], kl1, s1);
            s1 = MFMA_16x16x32(qfl[c], kh1, s1);
        }
        const int irow0 = q0 + w*16 + lhi*4;
        const int j0 = kt*32 + l15;
        float ef[4];
        #pragma unroll
        for (int r = 0; r < 4; ++r) {
            float a0 = s0[r] * 0.08838834764831845f;
            float a1 = s1[r] * 0.08838834764831845f;
            const int ir = irow0 + r;
            if (j0 > ir) a0 = -1e30f;
            if (j0 + 16 > ir) a1 = -1e30f;
            float mx = fmaxf(a0, a1);
            #pragma unroll
            for (int o = 1; o < 16; o <<= 1) mx = fmaxf(mx, __shfl_xor(mx, o));
            float mn = fmaxf(m_r[r], mx);
            ef[r] = __expf(m_r[r] - mn);
            m_r[r] = mn;
            float p0 = __expf(a0 - mn);
            float p1 = __expf(a1 - mn);
            float ps = p0 + p1;
            #pragma unroll
            for (int o = 1; o < 16; o <<= 1) ps += __shfl_xor(ps, o);
            l_r[r] = l_r[r]*ef[r] + ps;
            fsplit(p0, Psh[w][lhi*4 + r][l15],      Psl[w][lhi*4 + r][l15]);
            fsplit(p1, Psh[w][lhi*4 + r][16 + l15], Psl[w][lhi*4 + r][16 + l15]);
        }
        #pragma unroll
        for (int ch = 0; ch < 8; ++ch) {
            f32x4 t = oacc[ch];
            t[0] *= ef[0]; t[1] *= ef[1]; t[2] *= ef[2]; t[3] *= ef[3];
            oacc[ch] = t;
        }
        __syncthreads();
        short8 pah = *(const short8*)&Psh[w][l15][lhi*8];
        short8 pal = *(const short8*)&Psl[w][l15][lhi*8];
        #pragma unroll
        for (int ch = 0; ch < 8; ++ch) {
            short8 bvh = *(const short8*)&Vsh[ch*16 + l15][lhi*8];
            short8 bvl = *(const short8*)&Vsl[ch*16 + l15][lhi*8];
            oacc[ch] = MFMA_16x16x32(pah, bvh, oacc[ch]);
            oacc[ch] = MFMA_16x16x32(pah, bvl, oacc[ch]);
            oacc[ch] = MFMA_16x16x32(pal, bvh, oacc[ch]);
        }
    }
    #pragma unroll
    for (int r = 0; r < 4; ++r) {
        const int row = q0 + w*16 + lhi*4 + r;
        const float inv = 1.0f / l_r[r];
        u16* oph = Oh + ((size_t)(b*SS + row)*HH + h)*HDD;
        u16* opl = Ol + ((size_t)(b*SS + row)*HH + h)*HDD;
        #pragma unroll
        for (int ch = 0; ch < 8; ++ch) {
            float o = oacc[ch][r] * inv;
            fsplit(o, oph[ch*16 + l15], opl[ch*16 + l15]);
        }
    }
}

// ---------------- Router: f32 logits, softmax, top-6, slot lists ------------
__global__ __launch_bounds__(256) void k_router(
    const float* __restrict__ X, const float* __restrict__ Wg,
    const float* __restrict__ bias,
    int* __restrict__ cnt, int* __restrict__ list, float* __restrict__ wts)
{
    const int t = blockIdx.x;
    const int e = threadIdx.x & 15, sl = threadIdx.x >> 4;
    const float* x = X + (size_t)t * DD;
    float part = 0.f;
    for (int i = 0; i < 128; ++i) {
        int k = sl * 128 + i;
        part += x[k] * Wg[(size_t)k * EE + e];
    }
    __shared__ float red[16][17];
    red[sl][e] = part;
    __syncthreads();
    if (threadIdx.x == 0) {
        float lg[16], pr[16];
        for (int ee = 0; ee < 16; ++ee) {
            float s = 0.f;
            for (int q = 0; q < 16; ++q) s += red[q][ee];
            lg[ee] = s;
        }
        float mx = lg[0];
        for (int ee = 1; ee < 16; ++ee) mx = fmaxf(mx, lg[ee]);
        float sum = 0.f;
        for (int ee = 0; ee < 16; ++ee) { pr[ee] = expf(lg[ee] - mx); sum += pr[ee]; }
        float isum = 1.0f / sum;
        for (int ee = 0; ee < 16; ++ee) pr[ee] *= isum;
        unsigned used = 0;
        int sel[NTOP]; float rw[NTOP]; float s6 = 0.f;
        for (int kk = 0; kk < NTOP; ++kk) {
            int best = 0; float bv = -1e30f;
            for (int ee = 0; ee < 16; ++ee) {
                if (used & (1u << ee)) continue;
                float sc = pr[ee] + bias[ee];
                if (sc > bv) { bv = sc; best = ee; }
            }
            used |= 1u << best;
            sel[kk] = best; rw[kk] = pr[best]; s6 += pr[best];
        }
        float inv6 = 1.0f / fmaxf(s6, 1e-12f);
        for (int kk = 0; kk < NTOP; ++kk) {
            int ee = sel[kk];
            int pos = atomicAdd(&cnt[ee], 1);
            list[ee*CAP + pos] = (t << 3) | kk;
            wts[ee*CAP + pos] = rw[kk] * inv6;
        }
    }
}

// ---------------- Final: out = h2 + shared + sum_kk routed ------------------
__global__ __launch_bounds__(256) void k_final(
    const float* __restrict__ h2, const float* __restrict__ yb,
    const u16* __restrict__ rb, float* __restrict__ out)
{
    int id = blockIdx.x * 256 + threadIdx.x;     // T*D/4
    size_t i4 = (size_t)id * 4;
    int t = id >> 9;
    int d = (id & 511) * 4;
    f32x4 acc = *(const f32x4*)(h2 + i4);
    f32x4 y = *(const f32x4*)(yb + i4);
    acc += y;
    #pragma unroll
    for (int kk = 0; kk < NTOP; ++kk) {
        s16x4 rv = *(const s16x4*)(rb + ((size_t)t*NTOP + kk)*DD + d);
        acc[0] += b2f((u16)rv[0]); acc[1] += b2f((u16)rv[1]);
        acc[2] += b2f((u16)rv[2]); acc[3] += b2f((u16)rv[3]);
    }
    *(f32x4*)(out + i4) = acc;
}

extern "C" void kernel_launch(void* const* d_in, const int* in_sizes, int n_in,
                              void* d_out, int out_size, void* d_ws, size_t ws_size,
                              hipStream_t stream)
{
    (void)in_sizes; (void)n_in; (void)out_size; (void)ws_size;
    const float* hidden = (const float*)d_in[0];
    const float* cosb   = (const float*)d_in[1];
    const float* sinb   = (const float*)d_in[2];
    const float* ln1    = (const float*)d_in[3];
    const float* ln2    = (const float*)d_in[4];
    const float* Wq     = (const float*)d_in[5];
    const float* Wk     = (const float*)d_in[6];
    const float* Wv     = (const float*)d_in[7];
    const float* Wo     = (const float*)d_in[8];
    const float* Wgate  = (const float*)d_in[9];
    const float* cbias  = (const float*)d_in[10];
    const float* Wg     = (const float*)d_in[11];
    const float* Wu     = (const float*)d_in[12];
    const float* Wd     = (const float*)d_in[13];
    const float* Wgs    = (const float*)d_in[14];
    const float* Wus    = (const float*)d_in[15];
    const float* Wds    = (const float*)d_in[16];
    float* out = (float*)d_out;

    char* ws = (char*)d_ws;
    size_t off = 0;
    auto alloc = [&](size_t bytes) {
        void* p = ws + off;
        off = (off + bytes + 255) & ~(size_t)255;
        return p;
    };
    // Pre-transposed bf16 weights
    u16* WqkvTh = (u16*)alloc((size_t)3072*2048*2);
    u16* WqkvTl = (u16*)alloc((size_t)3072*2048*2);
    u16* WoTh   = (u16*)alloc((size_t)2048*2048*2);
    u16* WoTl   = (u16*)alloc((size_t)2048*2048*2);
    u16* WgsT   = (u16*)alloc((size_t)2048*2048*2);
    u16* WusT   = (u16*)alloc((size_t)2048*2048*2);
    u16* WdsT   = (u16*)alloc((size_t)2048*2048*2);
    u16* WgT    = (u16*)alloc((size_t)EE*II*DD*2);
    u16* WuT    = (u16*)alloc((size_t)EE*II*DD*2);
    u16* WdT    = (u16*)alloc((size_t)EE*DD*II*2);
    // Activations
    u16*   x1h  = (u16*)  alloc((size_t)TT*DD*2);
    u16*   x1l  = (u16*)  alloc((size_t)TT*DD*2);
    float* qkvf = (float*)alloc((size_t)TT*3072*4);
    u16*   qh   = (u16*)  alloc((size_t)TT*HH*HDD*2);
    u16*   ql   = (u16*)  alloc((size_t)TT*HH*HDD*2);
    u16*   kh   = (u16*)  alloc((size_t)TT*HKK*HDD*2);
    u16*   kl   = (u16*)  alloc((size_t)TT*HKK*HDD*2);
    u16*   vth  = (u16*)  alloc((size_t)TT*HKK*HDD*2);
    u16*   vtl  = (u16*)  alloc((size_t)TT*HKK*HDD*2);
    u16*   aoh  = (u16*)  alloc((size_t)TT*HH*HDD*2);
    u16*   aol  = (u16*)  alloc((size_t)TT*HH*HDD*2);
    float* h2   = (float*)alloc((size_t)TT*DD*4);
    u16*   x2   = (u16*)  alloc((size_t)TT*DD*2);
    float* x2f  = (float*)alloc((size_t)TT*DD*4);
    int*   cnt  = (int*)  alloc(256);
    int*   lst  = (int*)  alloc((size_t)EE*CAP*4);
    float* wts  = (float*)alloc((size_t)EE*CAP*4);
    u16*   hE   = (u16*)  alloc((size_t)EE*CAP*II*2);
    u16*   rbuf = (u16*)  alloc((size_t)TT*NTOP*DD*2);
    // Aliases (lifetimes disjoint):
    u16*   hs   = x1h;            // [TT][ISS] bf16 = 8MB, x1h dead after QKV
    float* ybuf = qkvf;           // [TT][DD] f32 = 16MB, qkvf dead after splits

    // ---- Weight prep (transpose + bf16 convert [+ split]) ----
    k_prep<true ><<<dim3(64,64,1), 256, 0, stream>>>(Wq, WqkvTh, WqkvTl, 2048, 2048);
    k_prep<true ><<<dim3(16,64,1), 256, 0, stream>>>(Wk, WqkvTh + (size_t)2048*2048, WqkvTl + (size_t)2048*2048, 2048, 512);
    k_prep<true ><<<dim3(16,64,1), 256, 0, stream>>>(Wv, WqkvTh + (size_t)2560*2048, WqkvTl + (size_t)2560*2048, 2048, 512);
    k_prep<true ><<<dim3(64,64,1), 256, 0, stream>>>(Wo, WoTh, WoTl, 2048, 2048);
    k_prep<false><<<dim3(64,64,1), 256, 0, stream>>>(Wgs, WgsT, nullptr, 2048, 2048);
    k_prep<false><<<dim3(64,64,1), 256, 0, stream>>>(Wus, WusT, nullptr, 2048, 2048);
    k_prep<false><<<dim3(64,64,1), 256, 0, stream>>>(Wds, WdsT, nullptr, 2048, 2048);
    k_prep<false><<<dim3(32,64,EE), 256, 0, stream>>>(Wg, WgT, nullptr, 2048, 1024);
    k_prep<false><<<dim3(32,64,EE), 256, 0, stream>>>(Wu, WuT, nullptr, 2048, 1024);
    k_prep<false><<<dim3(64,32,EE), 256, 0, stream>>>(Wd, WdT, nullptr, 1024, 2048);

    // ---- Attention path (split-bf16 high precision) ----
    k_rmsnorm_split<<<TT, 256, 0, stream>>>(hidden, ln1, x1h, x1l);
    k_gemm_hi<2><<<dim3(24,16), 256, 0, stream>>>(x1h, x1l, WqkvTh, WqkvTl, qkvf, nullptr, TT, 3072, DD);
    k_rope_split<<<(TT*20*64)/256, 256, 0, stream>>>(qkvf, cosb, sinb, qh, ql, kh, kl);
    k_split_vt<<<(TT*HKK*HDD/8)/256, 256, 0, stream>>>(qkvf, vth, vtl);
    k_attn_hi<<<dim3(SS/64, BB*HH), 256, 0, stream>>>(qh, ql, kh, kl, vth, vtl, aoh, aol);
    k_gemm_hi<1><<<dim3(16,16), 256, 0, stream>>>(aoh, aol, WoTh, WoTl, h2, hidden, TT, DD, HH*HDD);

    // ---- MoE path ----
    k_rmsnorm_bf<<<TT, 256, 0, stream>>>(h2, ln2, x2, x2f);
    (void)hipMemsetAsync(cnt, 0, 256, stream);
    k_router<<<TT, 256, 0, stream>>>(x2f, Wgate, cbias, cnt, lst, wts);
    k_glu<false><<<dim3(ISS/64, TT/128, 1), 256, 0, stream>>>(x2, WgsT, WusT, hs, nullptr, nullptr, TT, ISS, DD);
    k_gemm<2><<<dim3(16,16), 256, 0, stream>>>(hs, WdsT, ybuf, TT, DD, ISS);
    k_glu<true><<<dim3(II/64, CAP/128, EE), 256, 0, stream>>>(x2, WgT, WuT, hE, lst, cnt, CAP, II, DD);
    k_down_scatter<<<dim3(DD/128, CAP/128, EE), 256, 0, stream>>>(hE, WdT, rbuf, lst, wts, cnt, DD, II);
    k_final<<<(TT*DD/4)/256, 256, 0, stream>>>(h2, ybuf, rbuf, out);
}